// Round 13
// baseline (256.329 us; speedup 1.0000x reference)
//
#include <hip/hip_runtime.h>
#include <cstddef>

#define KN 9
typedef unsigned short u16;
typedef unsigned int u32;
typedef __attribute__((ext_vector_type(8))) short short8;
typedef __attribute__((ext_vector_type(4))) float f32x4;

__device__ inline u16 f2b(float f) {
    union { float f; u32 u; } v; v.f = f;
    u32 r = v.u + 0x7FFFu + ((v.u >> 16) & 1u);
    return (u16)(r >> 16);
}
__device__ inline float b2f(u16 h) {
    union { u32 u; float f; } v; v.u = ((u32)h) << 16; return v.f;
}

// bijective XCD-aware block swizzle (m204)
__device__ inline int xcd_swz(int bid, int n) {
    int q = n >> 3, r = n & 7;
    int x = bid & 7, pos = bid >> 3;
    return (x < r ? x * (q + 1) : r * (q + 1) + (x - r) * q) + pos;
}

// ---------------------------------------------------------------------------
// all 6 one-hot pool matrices -> gather indices
// ---------------------------------------------------------------------------
__global__ void extract_idx_all(
    const float* __restrict__ D0, const float* __restrict__ D1, const float* __restrict__ D2,
    const float* __restrict__ U0, const float* __restrict__ U1, const float* __restrict__ U2,
    int* __restrict__ iD0, int* __restrict__ iD1, int* __restrict__ iD2,
    int* __restrict__ iU0, int* __restrict__ iU1, int* __restrict__ iU2)
{
    int blk = blockIdx.x;
    const float* L; int M; int* out; int p;
    if      (blk < 1257) { L = D0; M = 5024; out = iD0; p = blk; }
    else if (blk < 1572) { L = D1; M = 1257; out = iD1; p = blk - 1257; }
    else if (blk < 1652) { L = D2; M = 315;  out = iD2; p = blk - 1572; }
    else if (blk < 6676) { L = U0; M = 1257; out = iU0; p = blk - 1652; }
    else if (blk < 7933) { L = U1; M = 315;  out = iU1; p = blk - 6676; }
    else                 { L = U2; M = 80;   out = iU2; p = blk - 7933; }
    const float* row = L + (size_t)p * M;
    for (int m = threadIdx.x; m < M; m += 256)
        if (row[m] > 0.5f) out[p] = m;
}

// ---------------------------------------------------------------------------
// zero f32 region (for split-K atomic accumulation), per launch
// ---------------------------------------------------------------------------
__global__ void zero_f32(float4* __restrict__ p, int n4)
{
    int t = blockIdx.x * 256 + threadIdx.x;
    if (t < n4) p[t] = (float4){0.f, 0.f, 0.f, 0.f};
}

// ---------------------------------------------------------------------------
// weight conversions + zbuf zeroing
// ---------------------------------------------------------------------------
__device__ inline void wcr_one(const float* __restrict__ wc, u16* __restrict__ out, int t, int F) {
    int FK = F * KN;
    int c = t / FK, rem = t - c * FK, j = rem / F, f = rem - j * F;
    out[t] = f2b(wc[(size_t)c * FK + f * KN + j]);
}
__device__ inline void wg_one(const float* __restrict__ wc, u16* __restrict__ out, int t, int F, int C) {
    int n = t / F, f = t - n * F;
    int j = n / C, c = n - j * C;
    out[t] = f2b(wc[(size_t)c * (F * KN) + f * KN + j]);
}
__device__ inline void ccw_one(const float* __restrict__ wm, u16* __restrict__ out, int t, int F) {
    int n = t / F, f = t - n * F;
    out[t] = (n < KN) ? f2b(wm[n * F + f]) : (u16)0;
}
__global__ void cvt_weights(
    const float* __restrict__ e1_wc, const float* __restrict__ e2_wc,
    const float* __restrict__ d0_wc, const float* __restrict__ d1_wc,
    const float* __restrict__ d0_wm, const float* __restrict__ d2_wm,
    const float* __restrict__ d2_wc,
    u16* __restrict__ wcrE1, u16* __restrict__ wcrE2,
    u16* __restrict__ wg0, u16* __restrict__ wg1,
    u16* __restrict__ ccwD0, u16* __restrict__ w3, float* __restrict__ zbuf)
{
    int t = blockIdx.x * 256 + threadIdx.x;
    if (t < 73728)  { wcr_one(e1_wc, wcrE1, t, 64);       return; } t -= 73728;
    if (t < 294912) { wcr_one(e2_wc, wcrE2, t, 128);      return; } t -= 294912;
    if (t < 294912) { wg_one(d0_wc, wg0, t, 256, 128);    return; } t -= 294912;
    if (t < 73728)  { wg_one(d1_wc, wg1, t, 128, 64);     return; } t -= 73728;
    if (t < 16384)  { ccw_one(d0_wm, ccwD0, t, 256);      return; } t -= 16384;
    if (t < 4096) {
        int n = t >> 6, k = t & 63;
        float v = 0.f;
        if (n < KN) v = d2_wm[n * 64 + k];
        else if (n >= 9 && n < 36) {
            int cj = n - 9, j = cj / 3, c = cj - j * 3;     // j-major
            v = d2_wc[(size_t)c * 576 + k * KN + j];
        }
        w3[t] = f2b(v);
        return;
    } t -= 4096;
    if (t < 8192) zbuf[t] = 0.f;
}

// ---------------------------------------------------------------------------
// composed neighbor tables (stride 12) + encoder pad masks
// ---------------------------------------------------------------------------
__global__ void compose_tables(
    const int* __restrict__ nbr0, const int* __restrict__ nbr1, const int* __restrict__ nbr2,
    const int* __restrict__ idxD1, const int* __restrict__ idxD2,
    const int* __restrict__ idxU0, const int* __restrict__ idxU1, const int* __restrict__ idxU2,
    int* __restrict__ nbrD1, int* __restrict__ nbrD2,
    int* __restrict__ nbrU2, int* __restrict__ nbrU1, int* __restrict__ nbrU0,
    int* __restrict__ maskE1, int* __restrict__ maskE2)
{
    int t = blockIdx.x * 256 + threadIdx.x;
    if (t < 2835)  { int p = t / 9, j = t - p * 9; nbrD1[p * 12 + j] = nbr1[idxD1[p] * 9 + j]; return; } t -= 2835;
    if (t < 720)   { int p = t / 9, j = t - p * 9; nbrD2[p * 12 + j] = nbr2[idxD2[p] * 9 + j]; return; } t -= 720;
    if (t < 2835)  { int p = t / 9, j = t - p * 9; nbrU2[p * 12 + j] = idxU2[nbr2[p * 9 + j]]; return; } t -= 2835;
    if (t < 11313) { int p = t / 9, j = t - p * 9; nbrU1[p * 12 + j] = idxU1[nbr1[p * 9 + j]]; return; } t -= 11313;
    if (t < 45216) { int p = t / 9, j = t - p * 9; nbrU0[p * 12 + j] = idxU0[nbr0[p * 9 + j]]; return; } t -= 45216;
    if (t < 315)   { maskE1[t] = (idxD1[t] == 1256) ? 1 : 0; return; } t -= 315;
    if (t < 80)    { maskE2[t] = (idxD2[t] == 314) ? 1 : 0; }
}

// ---------------------------------------------------------------------------
// cc GEMM (kept only for CCD0): out[m][nn<NW] f32, row stride OS
// ---------------------------------------------------------------------------
template<int NW, int OS>
__global__ __launch_bounds__(256) void cc_gemm(
    const u16* __restrict__ A, const u16* __restrict__ W,
    float* __restrict__ out, int M, int F)
{
    __shared__ u16 As[64 * 72];
    __shared__ u16 Ws[64 * 72];
    int tid = threadIdx.x;
    int mT = blockIdx.x * 64;
    int wid = tid >> 6, lane = tid & 63;
    int wr = wid >> 1, wcq = wid & 1;
    int r = lane & 15, g = lane >> 4;
    f32x4 acc[2][2];
    #pragma unroll
    for (int i = 0; i < 2; ++i)
        #pragma unroll
        for (int j = 0; j < 2; ++j)
            acc[i][j] = (f32x4){0.f, 0.f, 0.f, 0.f};

    for (int k0 = 0; k0 < F; k0 += 64) {
        #pragma unroll
        for (int h = 0; h < 2; ++h) {
            int gi = tid + h * 256;
            int m = gi >> 3, kg = gi & 7;
            uint4 va = {0u, 0u, 0u, 0u};
            int row = mT + m;
            if (row < M) va = *(const uint4*)(A + (size_t)row * F + k0 + kg * 8);
            *(uint4*)&As[m * 72 + kg * 8] = va;
            *(uint4*)&Ws[m * 72 + kg * 8] = *(const uint4*)(W + (size_t)m * F + k0 + kg * 8);
        }
        __syncthreads();
        #pragma unroll
        for (int S = 0; S < 2; ++S) {
            short8 af[2], bf[2];
            #pragma unroll
            for (int R = 0; R < 2; ++R)
                af[R] = *(const short8*)&As[(wr * 32 + R * 16 + r) * 72 + S * 32 + g * 8];
            #pragma unroll
            for (int C2 = 0; C2 < 2; ++C2)
                bf[C2] = *(const short8*)&Ws[(wcq * 32 + C2 * 16 + r) * 72 + S * 32 + g * 8];
            #pragma unroll
            for (int R = 0; R < 2; ++R)
                #pragma unroll
                for (int C2 = 0; C2 < 2; ++C2)
                    acc[R][C2] = __builtin_amdgcn_mfma_f32_16x16x32_bf16(af[R], bf[C2], acc[R][C2], 0, 0, 0);
        }
        __syncthreads();
    }
    #pragma unroll
    for (int R = 0; R < 2; ++R)
        #pragma unroll
        for (int C2 = 0; C2 < 2; ++C2)
            #pragma unroll
            for (int q = 0; q < 4; ++q) {
                int mm = mT + wr * 32 + R * 16 + g * 4 + q;
                int nn = wcq * 32 + C2 * 16 + r;
                if (mm < M && nn < NW)
                    out[(size_t)mm * OS + nn] = acc[R][C2][q];
            }
}

// ---------------------------------------------------------------------------
// d2 cc+gw GEMM, transposed outputs: CCT[p][f][b]; GWT[p][j][b][4] (c<3)
// ---------------------------------------------------------------------------
__global__ __launch_bounds__(256) void cc_gemmT(
    const u16* __restrict__ A, const u16* __restrict__ W,
    float* __restrict__ CCT, float* __restrict__ GWT, int M)
{
    __shared__ u16 As[64 * 72];
    __shared__ u16 Ws[64 * 72];
    int tid = threadIdx.x;
    int mT = blockIdx.x * 64;
    int wid = tid >> 6, lane = tid & 63;
    int wr = wid >> 1, wcq = wid & 1;
    int r = lane & 15, g = lane >> 4;
    f32x4 acc[2][2];
    #pragma unroll
    for (int i = 0; i < 2; ++i)
        #pragma unroll
        for (int j = 0; j < 2; ++j)
            acc[i][j] = (f32x4){0.f, 0.f, 0.f, 0.f};

    {
        #pragma unroll
        for (int h = 0; h < 2; ++h) {
            int gi = tid + h * 256;
            int m = gi >> 3, kg = gi & 7;
            uint4 va = {0u, 0u, 0u, 0u};
            int row = mT + m;
            if (row < M) va = *(const uint4*)(A + (size_t)row * 64 + kg * 8);
            *(uint4*)&As[m * 72 + kg * 8] = va;
            *(uint4*)&Ws[m * 72 + kg * 8] = *(const uint4*)(W + (size_t)m * 64 + kg * 8);
        }
        __syncthreads();
        #pragma unroll
        for (int S = 0; S < 2; ++S) {
            short8 af[2], bf[2];
            #pragma unroll
            for (int R = 0; R < 2; ++R)
                af[R] = *(const short8*)&As[(wr * 32 + R * 16 + r) * 72 + S * 32 + g * 8];
            #pragma unroll
            for (int C2 = 0; C2 < 2; ++C2)
                bf[C2] = *(const short8*)&Ws[(wcq * 32 + C2 * 16 + r) * 72 + S * 32 + g * 8];
            #pragma unroll
            for (int R = 0; R < 2; ++R)
                #pragma unroll
                for (int C2 = 0; C2 < 2; ++C2)
                    acc[R][C2] = __builtin_amdgcn_mfma_f32_16x16x32_bf16(af[R], bf[C2], acc[R][C2], 0, 0, 0);
        }
    }
    #pragma unroll
    for (int R = 0; R < 2; ++R)
        #pragma unroll
        for (int C2 = 0; C2 < 2; ++C2)
            #pragma unroll
            for (int q = 0; q < 4; ++q) {
                int mm = mT + wr * 32 + R * 16 + g * 4 + q;
                if (mm >= M) continue;
                int nn = wcq * 32 + C2 * 16 + r;
                if (nn >= 36) continue;
                int b = mm / 1257, p = mm - b * 1257;
                float val = acc[R][C2][q];
                if (nn < 9) {
                    CCT[((size_t)p * 9 + nn) * 32 + b] = val;
                } else {
                    int cj = nn - 9, j = cj / 3, c = cj - j * 3;
                    GWT[(size_t)p * 1152 + j * 128 + b * 4 + c] = val;
                }
            }
}

// ---------------------------------------------------------------------------
// GEMM, LDS double-buffered (decoder G-GEMMs)
// ---------------------------------------------------------------------------
template<int ACT, int MASK>
__global__ __launch_bounds__(256) void lin_gemm(
    const u16* __restrict__ A, const u16* __restrict__ W,
    const float* __restrict__ bias, u16* __restrict__ Y,
    const int* __restrict__ maskT,
    int M, int K, int N, int P)
{
    __shared__ u16 As[2][64 * 72];
    __shared__ u16 Ws[2][64 * 72];
    int tid = threadIdx.x;
    int mT = blockIdx.x * 64, nT = blockIdx.y * 64;
    int wid = tid >> 6, lane = tid & 63;
    int wr = wid >> 1, wcq = wid & 1;
    int r = lane & 15, g = lane >> 4;
    int lm = tid >> 3, lkg = tid & 7;
    f32x4 acc[2][2];
    #pragma unroll
    for (int i = 0; i < 2; ++i)
        #pragma unroll
        for (int j = 0; j < 2; ++j)
            acc[i][j] = (f32x4){0.f, 0.f, 0.f, 0.f};

    uint4 ra[2], rw[2];
    #pragma unroll
    for (int h = 0; h < 2; ++h) {
        int m = lm + h * 32;
        int row = mT + m;
        uint4 z; z.x = z.y = z.z = z.w = 0u;
        ra[h] = (row < M) ? *(const uint4*)(A + (size_t)row * K + lkg * 8) : z;
        rw[h] = *(const uint4*)(W + (size_t)(nT + m) * K + lkg * 8);
    }
    #pragma unroll
    for (int h = 0; h < 2; ++h) {
        int m = lm + h * 32;
        *(uint4*)&As[0][m * 72 + lkg * 8] = ra[h];
        *(uint4*)&Ws[0][m * 72 + lkg * 8] = rw[h];
    }

    int cur = 0;
    for (int k0 = 0; k0 < K; k0 += 64) {
        __syncthreads();
        bool more = (k0 + 64 < K);
        if (more) {
            int kn = k0 + 64;
            #pragma unroll
            for (int h = 0; h < 2; ++h) {
                int m = lm + h * 32;
                int row = mT + m;
                uint4 z; z.x = z.y = z.z = z.w = 0u;
                ra[h] = (row < M) ? *(const uint4*)(A + (size_t)row * K + kn + lkg * 8) : z;
                rw[h] = *(const uint4*)(W + (size_t)(nT + m) * K + kn + lkg * 8);
            }
        }
        #pragma unroll
        for (int S = 0; S < 2; ++S) {
            short8 af[2], bf[2];
            #pragma unroll
            for (int R = 0; R < 2; ++R)
                af[R] = *(const short8*)&As[cur][(wr * 32 + R * 16 + r) * 72 + S * 32 + g * 8];
            #pragma unroll
            for (int C2 = 0; C2 < 2; ++C2)
                bf[C2] = *(const short8*)&Ws[cur][(wcq * 32 + C2 * 16 + r) * 72 + S * 32 + g * 8];
            #pragma unroll
            for (int R = 0; R < 2; ++R)
                #pragma unroll
                for (int C2 = 0; C2 < 2; ++C2)
                    acc[R][C2] = __builtin_amdgcn_mfma_f32_16x16x32_bf16(af[R], bf[C2], acc[R][C2], 0, 0, 0);
        }
        if (more) {
            #pragma unroll
            for (int h = 0; h < 2; ++h) {
                int m = lm + h * 32;
                *(uint4*)&As[cur ^ 1][m * 72 + lkg * 8] = ra[h];
                *(uint4*)&Ws[cur ^ 1][m * 72 + lkg * 8] = rw[h];
            }
        }
        cur ^= 1;
    }

    #pragma unroll
    for (int R = 0; R < 2; ++R)
        #pragma unroll
        for (int C2 = 0; C2 < 2; ++C2)
            #pragma unroll
            for (int q = 0; q < 4; ++q) {
                int mm = mT + wr * 32 + R * 16 + g * 4 + q;
                if (mm >= M) continue;
                int nn = nT + wcq * 32 + C2 * 16 + r;
                float v = acc[R][C2][q];
                if (bias) v += bias[nn];
                if (ACT == 1) v = v > 0.f ? v : expm1f(v);
                if (MASK) { if (maskT[mm % P] != 0) v = 0.f; }
                Y[(size_t)mm * N + nn] = f2b(v);
            }
}

// ---------------------------------------------------------------------------
// split-K GEMM: partials atomicAdd'ed into pre-zeroed f32 Yf.
// ---------------------------------------------------------------------------
__global__ __launch_bounds__(256) void lin_gemm_sk(
    const u16* __restrict__ A, const u16* __restrict__ W,
    float* __restrict__ Yf, int M, int K, int N, int KSTEPS)
{
    __shared__ u16 As[64 * 72];
    __shared__ u16 Ws[64 * 72];
    int tid = threadIdx.x;
    int mT = blockIdx.x * 64, nT = blockIdx.y * 64;
    int kbase = blockIdx.z * KSTEPS * 64;
    int wid = tid >> 6, lane = tid & 63;
    int wr = wid >> 1, wcq = wid & 1;
    int r = lane & 15, g = lane >> 4;
    f32x4 acc[2][2];
    #pragma unroll
    for (int i = 0; i < 2; ++i)
        #pragma unroll
        for (int j = 0; j < 2; ++j)
            acc[i][j] = (f32x4){0.f, 0.f, 0.f, 0.f};

    for (int s = 0; s < KSTEPS; ++s) {
        int k0 = kbase + s * 64;
        #pragma unroll
        for (int h = 0; h < 2; ++h) {
            int gi = tid + h * 256;
            int m = gi >> 3, kg = gi & 7;
            uint4 va = {0u, 0u, 0u, 0u};
            int row = mT + m;
            if (row < M) va = *(const uint4*)(A + (size_t)row * K + k0 + kg * 8);
            *(uint4*)&As[m * 72 + kg * 8] = va;
            *(uint4*)&Ws[m * 72 + kg * 8] = *(const uint4*)(W + (size_t)(nT + m) * K + k0 + kg * 8);
        }
        __syncthreads();
        #pragma unroll
        for (int S = 0; S < 2; ++S) {
            short8 af[2], bf[2];
            #pragma unroll
            for (int R = 0; R < 2; ++R)
                af[R] = *(const short8*)&As[(wr * 32 + R * 16 + r) * 72 + S * 32 + g * 8];
            #pragma unroll
            for (int C2 = 0; C2 < 2; ++C2)
                bf[C2] = *(const short8*)&Ws[(wcq * 32 + C2 * 16 + r) * 72 + S * 32 + g * 8];
            #pragma unroll
            for (int R = 0; R < 2; ++R)
                #pragma unroll
                for (int C2 = 0; C2 < 2; ++C2)
                    acc[R][C2] = __builtin_amdgcn_mfma_f32_16x16x32_bf16(af[R], bf[C2], acc[R][C2], 0, 0, 0);
        }
        __syncthreads();
    }
    #pragma unroll
    for (int R = 0; R < 2; ++R)
        #pragma unroll
        for (int C2 = 0; C2 < 2; ++C2)
            #pragma unroll
            for (int q = 0; q < 4; ++q) {
                int mm = mT + wr * 32 + R * 16 + g * 4 + q;
                if (mm >= M) continue;
                int nn = nT + wcq * 32 + C2 * 16 + r;
                atomicAdd(&Yf[(size_t)mm * N + nn], acc[R][C2][q]);
            }
}

// ---------------------------------------------------------------------------
// split-K epilogue: bias + ELU + mask + bf16 (4 elems/thread).
// WITHCC: also emit cc[row][i<9] = sum_n wmcc[i][n]*y[n] (32-lane reduce; N=128)
// ---------------------------------------------------------------------------
template<int WITHCC>
__global__ __launch_bounds__(256) void elu_mask_cvt(
    const float* __restrict__ Yf, const float* __restrict__ bias,
    const int* __restrict__ maskT, u16* __restrict__ Y,
    const float* __restrict__ wmcc, float* __restrict__ ccout,
    int M, int N, int P)
{
    int t = blockIdx.x * 256 + threadIdx.x;
    int tot = (M * N) >> 2;
    bool act = t < tot;
    int e0 = act ? t * 4 : 0;
    int m = e0 / N, n0 = e0 - m * N;
    float o0 = 0.f, o1 = 0.f, o2 = 0.f, o3 = 0.f;
    if (act) {
        float4 v = ((const float4*)Yf)[t];
        o0 = v.x + bias[n0];
        o1 = v.y + bias[n0 + 1];
        o2 = v.z + bias[n0 + 2];
        o3 = v.w + bias[n0 + 3];
        o0 = o0 > 0.f ? o0 : expm1f(o0);
        o1 = o1 > 0.f ? o1 : expm1f(o1);
        o2 = o2 > 0.f ? o2 : expm1f(o2);
        o3 = o3 > 0.f ? o3 : expm1f(o3);
        if (maskT[m % P] != 0) { o0 = 0.f; o1 = 0.f; o2 = 0.f; o3 = 0.f; }
        uint2 o;
        o.x = (u32)f2b(o0) | ((u32)f2b(o1) << 16);
        o.y = (u32)f2b(o2) | ((u32)f2b(o3) << 16);
        ((uint2*)Y)[t] = o;
    }
    if (WITHCC) {
        // N must be 128: row = 32 consecutive threads (half-wave aligned)
        int lane = threadIdx.x & 63;
        #pragma unroll
        for (int i = 0; i < KN; ++i) {
            float pr = 0.f;
            if (act) {
                const float* wr2 = wmcc + i * 128 + n0;
                pr = o0 * wr2[0] + o1 * wr2[1] + o2 * wr2[2] + o3 * wr2[3];
            }
            pr += __shfl_xor(pr, 16, 64);
            pr += __shfl_xor(pr, 8, 64);
            pr += __shfl_xor(pr, 4, 64);
            pr += __shfl_xor(pr, 2, 64);
            pr += __shfl_xor(pr, 1, 64);
            if (act && (lane & 31) == 0)
                ccout[(size_t)m * 16 + i] = pr;
        }
    }
}

// ---------------------------------------------------------------------------
// fce via split-K MFMA (f32 weights converted in-register)
// ---------------------------------------------------------------------------
__global__ __launch_bounds__(256) void fce_mfma(
    const u16* __restrict__ A, const float* __restrict__ Wf,
    const float* __restrict__ bias, float* __restrict__ z)
{
    __shared__ u16 As[32 * 72];
    __shared__ u16 Ws[64 * 72];
    int tid = threadIdx.x;
    int nT = blockIdx.x * 64;
    int kbase = blockIdx.y * 256;
    int wv = tid >> 6, lane = tid & 63;
    int r = lane & 15, g = lane >> 4;
    int m = tid >> 3, kg = tid & 7;
    f32x4 acc[2];
    acc[0] = (f32x4){0.f, 0.f, 0.f, 0.f};
    acc[1] = (f32x4){0.f, 0.f, 0.f, 0.f};

    for (int ks = 0; ks < 4; ++ks) {
        int k0 = kbase + ks * 64;
        *(uint4*)&As[m * 72 + kg * 8] = *(const uint4*)(A + (size_t)m * 20480 + k0 + kg * 8);
        #pragma unroll
        for (int h = 0; h < 2; ++h) {
            int row = m + h * 32;
            const float* wr2 = Wf + (size_t)(nT + row) * 20480 + k0 + kg * 8;
            float4 w0 = *(const float4*)(wr2);
            float4 w1 = *(const float4*)(wr2 + 4);
            u16 o[8] = { f2b(w0.x), f2b(w0.y), f2b(w0.z), f2b(w0.w),
                         f2b(w1.x), f2b(w1.y), f2b(w1.z), f2b(w1.w) };
            *(uint4*)&Ws[row * 72 + kg * 8] = *(const uint4*)o;
        }
        __syncthreads();
        #pragma unroll
        for (int S = 0; S < 2; ++S) {
            short8 bfr = *(const short8*)&Ws[(wv * 16 + r) * 72 + S * 32 + g * 8];
            #pragma unroll
            for (int R = 0; R < 2; ++R) {
                short8 af = *(const short8*)&As[(R * 16 + r) * 72 + S * 32 + g * 8];
                acc[R] = __builtin_amdgcn_mfma_f32_16x16x32_bf16(af, bfr, acc[R], 0, 0, 0);
            }
        }
        __syncthreads();
    }
    #pragma unroll
    for (int R = 0; R < 2; ++R)
        #pragma unroll
        for (int q = 0; q < 4; ++q) {
            int mm = R * 16 + g * 4 + q;
            int nn = nT + wv * 16 + r;
            float v = acc[R][q];
            if (blockIdx.y == 0) v += bias[nn];
            atomicAdd(&z[mm * 256 + nn], v);
        }
}

// ---------------------------------------------------------------------------
// fcd via MFMA (both operands f32 -> bf16 in-register)
// ---------------------------------------------------------------------------
__global__ __launch_bounds__(256) void fcd_mfma(
    const float* __restrict__ Af, const float* __restrict__ Wf,
    const float* __restrict__ bias, u16* __restrict__ Y)
{
    __shared__ u16 As[64 * 72];
    __shared__ u16 Ws[64 * 72];
    int tid = threadIdx.x;
    int nT = blockIdx.x * 64;
    int wid = tid >> 6, lane = tid & 63;
    int wr = wid >> 1, wcq = wid & 1;
    int r = lane & 15, g = lane >> 4;
    int m = tid >> 3, kg = tid & 7;
    f32x4 acc[2][2];
    #pragma unroll
    for (int i = 0; i < 2; ++i)
        #pragma unroll
        for (int j = 0; j < 2; ++j)
            acc[i][j] = (f32x4){0.f, 0.f, 0.f, 0.f};

    for (int k0 = 0; k0 < 256; k0 += 64) {
        {
            const float* ar = Af + (size_t)m * 256 + k0 + kg * 8;
            float4 a0 = *(const float4*)(ar);
            float4 a1 = *(const float4*)(ar + 4);
            u16 o[8] = { f2b(a0.x), f2b(a0.y), f2b(a0.z), f2b(a0.w),
                         f2b(a1.x), f2b(a1.y), f2b(a1.z), f2b(a1.w) };
            *(uint4*)&As[m * 72 + kg * 8] = *(const uint4*)o;
            uint4 z4; z4.x = z4.y = z4.z = z4.w = 0u;
            *(uint4*)&As[(m + 32) * 72 + kg * 8] = z4;
        }
        #pragma unroll
        for (int h = 0; h < 2; ++h) {
            int row = m + h * 32;
            const float* wr2 = Wf + (size_t)(nT + row) * 256 + k0 + kg * 8;
            float4 w0 = *(const float4*)(wr2);
            float4 w1 = *(const float4*)(wr2 + 4);
            u16 o[8] = { f2b(w0.x), f2b(w0.y), f2b(w0.z), f2b(w0.w),
                         f2b(w1.x), f2b(w1.y), f2b(w1.z), f2b(w1.w) };
            *(uint4*)&Ws[row * 72 + kg * 8] = *(const uint4*)o;
        }
        __syncthreads();
        #pragma unroll
        for (int S = 0; S < 2; ++S) {
            short8 af[2], bf[2];
            #pragma unroll
            for (int R = 0; R < 2; ++R)
                af[R] = *(const short8*)&As[(wr * 32 + R * 16 + r) * 72 + S * 32 + g * 8];
            #pragma unroll
            for (int C2 = 0; C2 < 2; ++C2)
                bf[C2] = *(const short8*)&Ws[(wcq * 32 + C2 * 16 + r) * 72 + S * 32 + g * 8];
            #pragma unroll
            for (int R = 0; R < 2; ++R)
                #pragma unroll
                for (int C2 = 0; C2 < 2; ++C2)
                    acc[R][C2] = __builtin_amdgcn_mfma_f32_16x16x32_bf16(af[R], bf[C2], acc[R][C2], 0, 0, 0);
        }
        __syncthreads();
    }
    #pragma unroll
    for (int R = 0; R < 2; ++R)
        #pragma unroll
        for (int C2 = 0; C2 < 2; ++C2)
            #pragma unroll
            for (int q = 0; q < 4; ++q) {
                int mm = wr * 32 + R * 16 + g * 4 + q;
                if (mm >= 32) continue;
                int nn = nT + wcq * 32 + C2 * 16 + r;
                float v = acc[R][C2][q] + bias[nn];
                Y[(size_t)mm * 20480 + nn] = f2b(v);
            }
}

// ---------------------------------------------------------------------------
// encoder feast agg (XCD-swizzled)
// ---------------------------------------------------------------------------
template<int F>
__global__ __launch_bounds__(256) void feast_agg(
    const u16* __restrict__ x, const float* __restrict__ cc,
    const int* __restrict__ nbrT, const float* __restrict__ bm,
    u16* __restrict__ agg, int Pin, int P, int Mtot)
{
    constexpr int FC = F / 64;
    __shared__ float s_p[4][81];
    __shared__ int s_nb[4][KN];
    int tid = threadIdx.x, wid = tid >> 6, lane = tid & 63;
    int row = xcd_swz(blockIdx.x, gridDim.x) * 4 + wid;
    bool aw = row < Mtot;
    int b = 0, p = 0;
    if (aw) { b = row / P; p = row - b * P; }
    if (aw && lane < KN) s_nb[wid][lane] = b * Pin + nbrT[p * 12 + lane];
    __syncthreads();

    if (aw && lane < KN) {
        int j = lane;
        const float* c0 = cc + (size_t)s_nb[wid][0] * 16;
        const float* cj = cc + (size_t)s_nb[wid][j] * 16;
        float L[KN];
        #pragma unroll
        for (int i = 0; i < KN; ++i) L[i] = bm[i] + cj[i] - c0[i];
        float mx = L[0];
        #pragma unroll
        for (int i = 1; i < KN; ++i) mx = fmaxf(mx, L[i]);
        float s = 0.f;
        #pragma unroll
        for (int i = 0; i < KN; ++i) { L[i] = __expf(L[i] - mx); s += L[i]; }
        float inv = 1.f / s;
        #pragma unroll
        for (int i = 0; i < KN; ++i) s_p[wid][i * KN + j] = L[i] * inv;
    }
    __syncthreads();

    if (aw) {
        float xn[KN][FC];
        #pragma unroll
        for (int i = 0; i < KN; ++i) {
            const u16* xr = x + (size_t)s_nb[wid][i] * F;
            #pragma unroll
            for (int c = 0; c < FC; ++c) xn[i][c] = b2f(xr[lane + c * 64]);
        }
        #pragma unroll
        for (int j = 0; j < KN; ++j) {
            float a[FC];
            #pragma unroll
            for (int c = 0; c < FC; ++c) a[c] = 0.f;
            #pragma unroll
            for (int i = 0; i < KN; ++i) {
                float pv = s_p[wid][i * KN + j];
                #pragma unroll
                for (int c = 0; c < FC; ++c) a[c] += xn[i][c] * pv;
            }
            u16* orow = agg + (size_t)row * (KN * F) + j * F;
            #pragma unroll
            for (int c = 0; c < FC; ++c) orow[lane + c * 64] = f2b(a[c]);
        }
    }
}

// ---------------------------------------------------------------------------
// decoder mix, 8-wide vectorized, register-bounded. Optional cc emission
// (ccout != nullptr, C=128 only): cc[row][i] via 16-lane group reduction.
// ---------------------------------------------------------------------------
template<int C>
__global__ __launch_bounds__(256, 4) void mix_feast_v(
    const u16* __restrict__ G, const float* __restrict__ cc,
    const int* __restrict__ nbrT, const float* __restrict__ bm,
    const float* __restrict__ bc, u16* __restrict__ y,
    const float* __restrict__ wmcc, float* __restrict__ ccout,
    int Pin, int P, int Mtot)
{
    constexpr int LPR = C / 8;
    constexpr int RPW = 64 / LPR;
    constexpr int RPB = 4 * RPW;
    constexpr int GS = KN * C;
    __shared__ float s_p[RPB][84];
    __shared__ int   s_nb[RPB][KN];
    __shared__ float s_wm[KN * 128];

    int tid = threadIdx.x, wid = tid >> 6, lane = tid & 63;
    int rowbase = xcd_swz(blockIdx.x, gridDim.x) * RPB;

    if (ccout) {
        for (int t = tid; t < KN * C; t += 256) s_wm[t] = wmcc[t];
    }
    for (int t = tid; t < RPB * KN; t += 256) {
        int rr = t / KN, j = t - rr * KN;
        int row = rowbase + rr;
        int v = 0;
        if (row < Mtot) {
            int b = row / P, p = row - b * P;
            v = b * Pin + nbrT[p * 12 + j];
        }
        s_nb[rr][j] = v;
    }
    __syncthreads();

    // softmax columns
    {
        int rl, j0;
        if (C == 64) { rl = wid * RPW + (lane >> 3); j0 = lane & 7; }
        else         { rl = wid * RPW + (lane >> 4); j0 = lane & 15; }
        int row = rowbase + rl;
        if (row < Mtot && j0 <= KN) {
            float cc0[KN], bmr[KN];
            const float* c0 = cc + (size_t)s_nb[rl][0] * 16;
            #pragma unroll
            for (int i = 0; i < KN; ++i) { cc0[i] = c0[i]; bmr[i] = bm[i]; }
            int nj = 1;
            int jl[2]; jl[0] = j0; jl[1] = -1;
            if (C == 64 && j0 == 0) { jl[1] = 8; nj = 2; }
            if (j0 >= KN) nj = 0;
            for (int t = 0; t < nj; ++t) {
                int j = jl[t];
                const float* cj = cc + (size_t)s_nb[rl][j] * 16;
                float L[KN];
                #pragma unroll
                for (int i = 0; i < KN; ++i) L[i] = bmr[i] + cj[i] - cc0[i];
                float mx = L[0];
                #pragma unroll
                for (int i = 1; i < KN; ++i) mx = fmaxf(mx, L[i]);
                float sm = 0.f;
                #pragma unroll
                for (int i = 0; i < KN; ++i) { L[i] = __expf(L[i] - mx); sm += L[i]; }
                float inv = 1.f / sm;
                #pragma unroll
                for (int i = 0; i < KN; ++i) s_p[rl][i * KN + j] = L[i] * inv;
            }
        }
    }
    __syncthreads();

    {
        int rl = wid * RPW + lane / LPR;
        int coff = (lane % LPR) * 8;
        int row = rowbase + rl;
        if (row >= Mtot) return;
        int b = row / P, p = row - b * P;
        (void)b;
        float acc[8];
        #pragma unroll
        for (int k = 0; k < 8; ++k) acc[k] = bc[coff + k];
        #pragma unroll 1
        for (int i = 0; i < KN; ++i) {
            const u16* gr = G + (size_t)s_nb[rl][i] * GS + coff;
            #pragma unroll
            for (int j = 0; j < KN; ++j) {
                uint4 gv = *(const uint4*)(gr + j * C);
                const u16* ge = (const u16*)&gv;
                float p0 = s_p[rl][i * KN + j];
                #pragma unroll
                for (int k = 0; k < 8; ++k) acc[k] += p0 * b2f(ge[k]);
            }
        }
        float vp[8];
        u16 o[8];
        #pragma unroll
        for (int k = 0; k < 8; ++k) {
            float v = acc[k];
            v = v > 0.f ? v : expm1f(v);
            if (p == P - 1) v = 0.f;
            vp[k] = v;
            o[k] = f2b(v);
        }
        *(uint4*)(y + (size_t)row * C + coff) = *(const uint4*)o;
        if (C == 128 && ccout) {
            #pragma unroll
            for (int i = 0; i < KN; ++i) {
                const float* wr2 = s_wm + i * 128 + coff;
                float pr = 0.f;
                #pragma unroll
                for (int k = 0; k < 8; ++k) pr += vp[k] * wr2[k];
                pr += __shfl_xor(pr, 8, 64);
                pr += __shfl_xor(pr, 4, 64);
                pr += __shfl_xor(pr, 2, 64);
                pr += __shfl_xor(pr, 1, 64);
                if ((lane & 15) == 0)
                    ccout[(size_t)row * 16 + i] = pr;
            }
        }
    }
}

// ---------------------------------------------------------------------------
// e0 fused feast (F=3 -> C=64) + CC1 emission, XCD-swizzled
// ---------------------------------------------------------------------------
__global__ __launch_bounds__(256) void feast_e0(
    const float* __restrict__ x, const int* __restrict__ nbr,
    const int* __restrict__ sel,
    const float* __restrict__ wm, const float* __restrict__ bm,
    const float* __restrict__ wcw, const float* __restrict__ bc,
    const float* __restrict__ wm1, float* __restrict__ cc1,
    u16* __restrict__ y,
    int Nin, int P, int Nlevel, int Mtot)
{
    constexpr int F = 3, C = 64, FS = 4, Q = 27;
    __shared__ float s_wm[KN * FS];
    __shared__ float s_wc[C * Q];
    __shared__ float s_bm[KN];
    __shared__ float s_wm1[KN * 64];
    __shared__ float s_xn[4][KN * FS];
    __shared__ float s_lg[4][81];
    __shared__ float s_pm[4][81];
    __shared__ float s_ag[4][Q];
    __shared__ int   s_idx[4][KN];

    int tid = threadIdx.x, wid = tid >> 6, lane = tid & 63;
    for (int t = tid; t < KN * F; t += 256) { int i = t / F, f = t - i * F; s_wm[i * FS + f] = wm[t]; }
    for (int t = tid; t < C * Q; t += 256) s_wc[t] = wcw[t];
    for (int t = tid; t < KN * 64; t += 256) s_wm1[t] = wm1[t];
    if (tid < KN) s_bm[tid] = bm[tid];

    int wg = xcd_swz(blockIdx.x, gridDim.x) * 4 + wid;
    bool aw = wg < Mtot;
    int b = 0, p = 0, n = 0;
    if (aw) {
        b = wg / P; p = wg - b * P;
        n = sel[p];
    }
    if (aw && lane < KN) s_idx[wid][lane] = nbr[n * KN + lane];
    __syncthreads();

    if (aw) {
        const float* xb = x + (size_t)b * Nin * F;
        for (int t = lane; t < KN * F; t += 64) {
            int i = t / F, f = t - i * F;
            s_xn[wid][i * FS + f] = xb[(size_t)s_idx[wid][i] * F + f];
        }
    }
    __syncthreads();

    if (aw) {
        for (int pr = lane; pr < 81; pr += 64) {
            int i = pr / KN, j = pr - i * KN;
            float acc = s_bm[i];
            for (int f = 0; f < F; ++f)
                acc += (s_xn[wid][j * FS + f] - s_xn[wid][f]) * s_wm[i * FS + f];
            s_lg[wid][pr] = acc;
        }
    }
    __syncthreads();

    if (aw && lane < KN) {
        int j = lane;
        float mx = -1e30f;
        #pragma unroll
        for (int i = 0; i < KN; ++i) mx = fmaxf(mx, s_lg[wid][i * KN + j]);
        float sm = 0.f, ev[KN];
        #pragma unroll
        for (int i = 0; i < KN; ++i) { ev[i] = __expf(s_lg[wid][i * KN + j] - mx); sm += ev[i]; }
        float inv = 1.f / sm;
        #pragma unroll
        for (int i = 0; i < KN; ++i) s_pm[wid][i * KN + j] = ev[i] * inv;
    }
    __syncthreads();

    if (aw) {
        for (int t = lane; t < Q; t += 64) {
            int f = t / KN, j = t - f * KN;
            float acc = 0.f;
            #pragma unroll
            for (int i = 0; i < KN; ++i) acc += s_xn[wid][i * FS + f] * s_pm[wid][i * KN + j];
            s_ag[wid][t] = acc;
        }
    }
    __syncthreads();

    if (aw) {
        int c = lane;
        float acc = 0.f;
        #pragma unroll
        for (int q = 0; q < Q; ++q)
            acc += s_wc[c * Q + q] * s_ag[wid][q];
        float val = acc + bc[c];
        val = val > 0.f ? val : expm1f(val);
        if (n == Nlevel - 1) val = 0.f;
        y[(size_t)wg * C + c] = f2b(val);
        // CC1[row][i] = wm1[i] . y[row]
        #pragma unroll
        for (int i = 0; i < KN; ++i) {
            float pr = val * s_wm1[i * 64 + lane];
            pr += __shfl_xor(pr, 32, 64);
            pr += __shfl_xor(pr, 16, 64);
            pr += __shfl_xor(pr, 8, 64);
            pr += __shfl_xor(pr, 4, 64);
            pr += __shfl_xor(pr, 2, 64);
            pr += __shfl_xor(pr, 1, 64);
            if (lane == 0) cc1[(size_t)wg * 16 + i] = pr;
        }
    }
}

// ---------------------------------------------------------------------------
// d2 mix, batch-coalesced; GWT stride 4 (float4 loads)
// ---------------------------------------------------------------------------
__global__ __launch_bounds__(256) void mix_d2t(
    const float* __restrict__ CCT, const float* __restrict__ GWT,
    const int* __restrict__ nbrT,
    const float* __restrict__ bm9, const float* __restrict__ bc3,
    float* __restrict__ out)
{
    __shared__ float s_out[8][32][3];
    int tid = threadIdx.x, wid = tid >> 6, lane = tid & 63;
    int sub = lane >> 5, b = lane & 31;
    int vbase = xcd_swz(blockIdx.x, gridDim.x) * 8;
    int v = vbase + wid * 2 + sub;

    int nbi[KN];
    #pragma unroll
    for (int i = 0; i < KN; ++i) nbi[i] = nbrT[v * 12 + i];
    float bmr[KN];
    #pragma unroll
    for (int i = 0; i < KN; ++i) bmr[i] = bm9[i];

    float cc0[KN];
    {
        const float* c0 = CCT + (size_t)nbi[0] * 9 * 32 + b;
        #pragma unroll
        for (int f = 0; f < KN; ++f) cc0[f] = c0[f * 32];
    }
    float a0 = bc3[0], a1 = bc3[1], a2 = bc3[2];
    #pragma unroll
    for (int j = 0; j < KN; ++j) {
        const float* cj = CCT + (size_t)nbi[j] * 9 * 32 + b;
        float L[KN];
        #pragma unroll
        for (int i = 0; i < KN; ++i) L[i] = bmr[i] + cj[i * 32] - cc0[i];
        float mx = L[0];
        #pragma unroll
        for (int i = 1; i < KN; ++i) mx = fmaxf(mx, L[i]);
        float sm = 0.f;
        #pragma unroll
        for (int i = 0; i < KN; ++i) { L[i] = __expf(L[i] - mx); sm += L[i]; }
        float inv = 1.f / sm;
        #pragma unroll
        for (int i = 0; i < KN; ++i) {
            float pv = L[i] * inv;
            float4 g = *(const float4*)(GWT + (size_t)nbi[i] * 1152 + j * 128 + b * 4);
            a0 += pv * g.x;
            a1 += pv * g.y;
            a2 += pv * g.z;
        }
    }
    if (v == 5023) { a0 = 0.f; a1 = 0.f; a2 = 0.f; }
    s_out[wid * 2 + sub][b][0] = a0;
    s_out[wid * 2 + sub][b][1] = a1;
    s_out[wid * 2 + sub][b][2] = a2;
    __syncthreads();
    {
        int bb = tid >> 3, vi = tid & 7;
        float* dst = out + ((size_t)bb * 5024 + vbase + vi) * 3;
        dst[0] = s_out[vi][bb][0];
        dst[1] = s_out[vi][bb][1];
        dst[2] = s_out[vi][bb][2];
    }
}

// ---------------------------------------------------------------------------
extern "C" void kernel_launch(void* const* d_in, const int* in_sizes, int n_in,
                              void* d_out, int out_size, void* d_ws, size_t ws_size,
                              hipStream_t stream)
{
    const float* x     = (const float*)d_in[0];
    const int*   nbr0  = (const int*)d_in[1];
    const int*   nbr1  = (const int*)d_in[2];
    const int*   nbr2  = (const int*)d_in[3];
    const float* D0    = (const float*)d_in[4];
    const float* U0    = (const float*)d_in[5];
    const float* D1    = (const float*)d_in[6];
    const float* U1    = (const float*)d_in[7];
    const float* D2    = (const float*)d_in[8];
    const float* U2    = (const float*)d_in[9];
    const float* e0_wm = (const float*)d_in[10]; const float* e0_bm = (const float*)d_in[11];
    const float* e0_wc = (const float*)d_in[12]; const float* e0_bc = (const float*)d_in[13];
    const float* e1_wm = (const float*)d_in[14]; const float* e1_bm = (const float*)d_in[15];
    const float* e1_wc = (const float*)d_in[16]; const float* e1_bc = (const float*)d_in[17];
    const float* e2_wm = (const float*)d_in[18]; const float* e2_bm = (const float*)d_in[19];
    const float* e2_wc = (const float*)d_in[20]; const float* e2_bc = (const float*)d_in[21];
    const float* fce_w = (const float*)d_in[22]; const float* fce_b = (const float*)d_in[23];
    const float* fcd_w = (const float*)d_in[24]; const float* fcd_b = (const float*)d_in[25];
    const float* d0_wm = (const float*)d_in[26]; const float* d0_bm = (const float*)d_in[27];
    const float* d0_wc = (const float*)d_in[28]; const float* d0_bc = (const float*)d_in[29];
    const float* d1_wm = (const float*)d_in[30]; const float* d1_bm = (const float*)d_in[31];
    const float* d1_wc = (const float*)d_in[32]; const float* d1_bc = (const float*)d_in[33];
    const float* d2_wm = (const float*)d_in[34]; const float* d2_bm = (const float*)d_in[35];
    const float* d2_wc = (const float*)d_in[36]; const float* d2_bc = (const float*)d_in[37];

    char* w = (char*)d_ws;
    int* idxD0 = (int*)(w);
    int* idxD1 = idxD0 + 1257;
    int* idxD2 = idxD1 + 315;
    int* idxU0 = idxD2 + 80;
    int* idxU1 = idxU0 + 5024;
    int* idxU2 = idxU1 + 1257;
    int* nbrD1  = (int*)(w + 33024);
    int* nbrD2  = (int*)(w + 48144);
    int* nbrU2  = (int*)(w + 51984);
    int* nbrU1  = (int*)(w + 67104);
    int* nbrU0  = (int*)(w + 127440);
    int* maskE1 = (int*)(w + 368640);
    int* maskE2 = (int*)(w + 369920);
    u16* wcrE1 = (u16*)(w + 370432);
    u16* wcrE2 = (u16*)(w + 517888);
    u16* wg0   = (u16*)(w + 1107712);
    u16* wg1   = (u16*)(w + 1697536);
    u16* ccwD0 = (u16*)(w + 1844992);     // 64*256*2 = 32768 -> 1877760
    u16* w3    = (u16*)(w + 1877760);     // 8192 -> 1885952
    float* zbuf = (float*)(w + 1886208);  // 32768 -> 1918976

    u16*   X1   = (u16*)  (w + 2097152);
    float* CC1  = (float*)(w + 7245824);
    u16*   AGG1 = (u16*)  (w + 9820160);
    u16*   X2   = (u16*)  (w + 21432320);
    float* CC2  = (float*)(w + 24012800);
    u16*   AGG2 = (u16*)  (w + 24657920);
    u16*   X3   = (u16*)  (w + 2097152);
    u16*   X3P  = (u16*)  (w + 3407872);
    float* CCD0 = (float*)(w + 4718592);
    u16*   G0   = (u16*)  (w + 4882432);
    u16*   XD1P = (u16*)  (w + 10780672);
    float* CCD1 = (float*)(w + 13361152);
    u16*   G1   = (u16*)  (w + 14006272);
    u16*   XD2P = (u16*)  (w + 25618432);
    float* CCT  = (float*)(w + 30767104);  // [1257][9][32]     -> 32215168
    float* GWT  = (float*)(w + 32215168);  // [1257][9][32][4]  -> 38007424
    float* X2F  = (float*)(w + 38007424);  // [10080][128] f32  -> 43168384
    float* X3F  = (float*)(w + 43168384);  // [2560][256] f32   -> 45789824

    // prep
    extract_idx_all<<<8248, 256, 0, stream>>>(D0, D1, D2, U0, U1, U2,
                                              idxD0, idxD1, idxD2, idxU0, idxU1, idxU2);
    cvt_weights<<<3072, 256, 0, stream>>>(e1_wc, e2_wc, d0_wc, d1_wc,
                                          d0_wm, d2_wm, d2_wc,
                                          wcrE1, wcrE2, wg0, wg1, ccwD0, w3, zbuf);
    compose_tables<<<248, 256, 0, stream>>>(nbr0, nbr1, nbr2,
                                            idxD1, idxD2, idxU0, idxU1, idxU2,
                                            nbrD1, nbrD2, nbrU2, nbrU1, nbrU0,
                                            maskE1, maskE2);
    zero_f32<<<1900, 256, 0, stream>>>((float4*)X2F, 486400);   // X2F + X3F

    // ---- encoder ----
    feast_e0<<<10056, 256, 0, stream>>>(x, nbr0, idxD0, e0_wm, e0_bm, e0_wc, e0_bc,
                                        e1_wm, CC1, X1, 5024, 1257, 5024, 40224);
    feast_agg<64><<<2520, 256, 0, stream>>>(X1, CC1, nbrD1, e1_bm, AGG1, 1257, 315, 10080);
    lin_gemm_sk<<<dim3(158, 2, 3), 256, 0, stream>>>(AGG1, wcrE1, X2F, 10080, 576, 128, 3);
    elu_mask_cvt<1><<<1260, 256, 0, stream>>>(X2F, e1_bc, maskE1, X2, e2_wm, CC2,
                                              10080, 128, 315);
    feast_agg<128><<<640, 256, 0, stream>>>(X2, CC2, nbrD2, e2_bm, AGG2, 315, 80, 2560);
    lin_gemm_sk<<<dim3(40, 4, 6), 256, 0, stream>>>(AGG2, wcrE2, X3F, 2560, 1152, 256, 3);
    elu_mask_cvt<0><<<640, 256, 0, stream>>>(X3F, e2_bc, maskE2, X3, nullptr, nullptr,
                                             2560, 256, 80);

    // ---- bottleneck ----
    fce_mfma<<<dim3(4, 80), 256, 0, stream>>>(X3, fce_w, fce_b, zbuf);
    fcd_mfma<<<320, 256, 0, stream>>>(zbuf, fcd_w, fcd_b, X3P);

    // ---- decoder ----
    cc_gemm<16, 16><<<40, 256, 0, stream>>>(X3P, ccwD0, CCD0, 2560, 256);
    lin_gemm<0, 0><<<dim3(40, 18), 256, 0, stream>>>(X3P, wg0, nullptr, G0, nullptr,
                                                     2560, 256, 1152, 1);
    mix_feast_v<128><<<630, 256, 0, stream>>>(G0, CCD0, nbrU2, d0_bm, d0_bc, XD1P,
                                              d1_wm, CCD1, 80, 315, 10080);
    lin_gemm<0, 0><<<dim3(158, 9), 256, 0, stream>>>(XD1P, wg1, nullptr, G1, nullptr,
                                                     10080, 128, 576, 1);
    mix_feast_v<64><<<1257, 256, 0, stream>>>(G1, CCD1, nbrU1, d1_bm, d1_bc, XD2P,
                                              nullptr, nullptr, 315, 1257, 40224);
    cc_gemmT<<<629, 256, 0, stream>>>(XD2P, w3, CCT, GWT, 40224);
    mix_d2t<<<628, 256, 0, stream>>>(CCT, GWT, nbrU0, d2_bm, d2_bc, (float*)d_out);
}

// Round 14
// 235.667 us; speedup vs baseline: 1.0877x; 1.0877x over previous
//
#include <hip/hip_runtime.h>
#include <cstddef>

#define KN 9
typedef unsigned short u16;
typedef unsigned int u32;
typedef __attribute__((ext_vector_type(8))) short short8;
typedef __attribute__((ext_vector_type(4))) float f32x4;

__device__ inline u16 f2b(float f) {
    union { float f; u32 u; } v; v.f = f;
    u32 r = v.u + 0x7FFFu + ((v.u >> 16) & 1u);
    return (u16)(r >> 16);
}
__device__ inline float b2f(u16 h) {
    union { u32 u; float f; } v; v.u = ((u32)h) << 16; return v.f;
}

// bijective XCD-aware block swizzle (m204)
__device__ inline int xcd_swz(int bid, int n) {
    int q = n >> 3, r = n & 7;
    int x = bid & 7, pos = bid >> 3;
    return (x < r ? x * (q + 1) : r * (q + 1) + (x - r) * q) + pos;
}

// ---------------------------------------------------------------------------
// all 6 one-hot pool matrices -> gather indices
// ---------------------------------------------------------------------------
__global__ void extract_idx_all(
    const float* __restrict__ D0, const float* __restrict__ D1, const float* __restrict__ D2,
    const float* __restrict__ U0, const float* __restrict__ U1, const float* __restrict__ U2,
    int* __restrict__ iD0, int* __restrict__ iD1, int* __restrict__ iD2,
    int* __restrict__ iU0, int* __restrict__ iU1, int* __restrict__ iU2)
{
    int blk = blockIdx.x;
    const float* L; int M; int* out; int p;
    if      (blk < 1257) { L = D0; M = 5024; out = iD0; p = blk; }
    else if (blk < 1572) { L = D1; M = 1257; out = iD1; p = blk - 1257; }
    else if (blk < 1652) { L = D2; M = 315;  out = iD2; p = blk - 1572; }
    else if (blk < 6676) { L = U0; M = 1257; out = iU0; p = blk - 1652; }
    else if (blk < 7933) { L = U1; M = 315;  out = iU1; p = blk - 6676; }
    else                 { L = U2; M = 80;   out = iU2; p = blk - 7933; }
    const float* row = L + (size_t)p * M;
    for (int m = threadIdx.x; m < M; m += 256)
        if (row[m] > 0.5f) out[p] = m;
}

// ---------------------------------------------------------------------------
// zero f32 region (for split-K atomic accumulation), per launch
// ---------------------------------------------------------------------------
__global__ void zero_f32(float4* __restrict__ p, int n4)
{
    int t = blockIdx.x * 256 + threadIdx.x;
    if (t < n4) p[t] = (float4){0.f, 0.f, 0.f, 0.f};
}

// ---------------------------------------------------------------------------
// weight conversions + zbuf zeroing
// ---------------------------------------------------------------------------
__device__ inline void wcr_one(const float* __restrict__ wc, u16* __restrict__ out, int t, int F) {
    int FK = F * KN;
    int c = t / FK, rem = t - c * FK, j = rem / F, f = rem - j * F;
    out[t] = f2b(wc[(size_t)c * FK + f * KN + j]);
}
__device__ inline void wg_one(const float* __restrict__ wc, u16* __restrict__ out, int t, int F, int C) {
    int n = t / F, f = t - n * F;
    int j = n / C, c = n - j * C;
    out[t] = f2b(wc[(size_t)c * (F * KN) + f * KN + j]);
}
__device__ inline void ccw_one(const float* __restrict__ wm, u16* __restrict__ out, int t, int F) {
    int n = t / F, f = t - n * F;
    out[t] = (n < KN) ? f2b(wm[n * F + f]) : (u16)0;
}
__global__ void cvt_weights(
    const float* __restrict__ e1_wc, const float* __restrict__ e2_wc,
    const float* __restrict__ d0_wc, const float* __restrict__ d1_wc,
    const float* __restrict__ e1_wm, const float* __restrict__ e2_wm,
    const float* __restrict__ d0_wm, const float* __restrict__ d1_wm,
    const float* __restrict__ d2_wm, const float* __restrict__ d2_wc,
    u16* __restrict__ wcrE1, u16* __restrict__ wcrE2,
    u16* __restrict__ wg0, u16* __restrict__ wg1,
    u16* __restrict__ ccwE1, u16* __restrict__ ccwE2,
    u16* __restrict__ ccwD0, u16* __restrict__ ccwD1,
    u16* __restrict__ w3, float* __restrict__ zbuf)
{
    int t = blockIdx.x * 256 + threadIdx.x;
    if (t < 73728)  { wcr_one(e1_wc, wcrE1, t, 64);       return; } t -= 73728;
    if (t < 294912) { wcr_one(e2_wc, wcrE2, t, 128);      return; } t -= 294912;
    if (t < 294912) { wg_one(d0_wc, wg0, t, 256, 128);    return; } t -= 294912;
    if (t < 73728)  { wg_one(d1_wc, wg1, t, 128, 64);     return; } t -= 73728;
    if (t < 4096)   { ccw_one(e1_wm, ccwE1, t, 64);       return; } t -= 4096;
    if (t < 8192)   { ccw_one(e2_wm, ccwE2, t, 128);      return; } t -= 8192;
    if (t < 16384)  { ccw_one(d0_wm, ccwD0, t, 256);      return; } t -= 16384;
    if (t < 8192)   { ccw_one(d1_wm, ccwD1, t, 128);      return; } t -= 8192;
    if (t < 4096) {
        int n = t >> 6, k = t & 63;
        float v = 0.f;
        if (n < KN) v = d2_wm[n * 64 + k];
        else if (n >= 9 && n < 36) {
            int cj = n - 9, j = cj / 3, c = cj - j * 3;     // j-major
            v = d2_wc[(size_t)c * 576 + k * KN + j];
        }
        w3[t] = f2b(v);
        return;
    } t -= 4096;
    if (t < 8192) zbuf[t] = 0.f;
}

// ---------------------------------------------------------------------------
// composed neighbor tables (stride 12) + encoder pad masks
// ---------------------------------------------------------------------------
__global__ void compose_tables(
    const int* __restrict__ nbr0, const int* __restrict__ nbr1, const int* __restrict__ nbr2,
    const int* __restrict__ idxD1, const int* __restrict__ idxD2,
    const int* __restrict__ idxU0, const int* __restrict__ idxU1, const int* __restrict__ idxU2,
    int* __restrict__ nbrD1, int* __restrict__ nbrD2,
    int* __restrict__ nbrU2, int* __restrict__ nbrU1, int* __restrict__ nbrU0,
    int* __restrict__ maskE1, int* __restrict__ maskE2)
{
    int t = blockIdx.x * 256 + threadIdx.x;
    if (t < 2835)  { int p = t / 9, j = t - p * 9; nbrD1[p * 12 + j] = nbr1[idxD1[p] * 9 + j]; return; } t -= 2835;
    if (t < 720)   { int p = t / 9, j = t - p * 9; nbrD2[p * 12 + j] = nbr2[idxD2[p] * 9 + j]; return; } t -= 720;
    if (t < 2835)  { int p = t / 9, j = t - p * 9; nbrU2[p * 12 + j] = idxU2[nbr2[p * 9 + j]]; return; } t -= 2835;
    if (t < 11313) { int p = t / 9, j = t - p * 9; nbrU1[p * 12 + j] = idxU1[nbr1[p * 9 + j]]; return; } t -= 11313;
    if (t < 45216) { int p = t / 9, j = t - p * 9; nbrU0[p * 12 + j] = idxU0[nbr0[p * 9 + j]]; return; } t -= 45216;
    if (t < 315)   { maskE1[t] = (idxD1[t] == 1256) ? 1 : 0; return; } t -= 315;
    if (t < 80)    { maskE2[t] = (idxD2[t] == 314) ? 1 : 0; }
}

// ---------------------------------------------------------------------------
// cc GEMM: out[m][nn<NW] = sum_f A[m][f]*W[nn][f]   (f32 out, row stride OS)
// ---------------------------------------------------------------------------
template<int NW, int OS>
__global__ __launch_bounds__(256) void cc_gemm(
    const u16* __restrict__ A, const u16* __restrict__ W,
    float* __restrict__ out, int M, int F)
{
    __shared__ u16 As[64 * 72];
    __shared__ u16 Ws[64 * 72];
    int tid = threadIdx.x;
    int mT = blockIdx.x * 64;
    int wid = tid >> 6, lane = tid & 63;
    int wr = wid >> 1, wcq = wid & 1;
    int r = lane & 15, g = lane >> 4;
    f32x4 acc[2][2];
    #pragma unroll
    for (int i = 0; i < 2; ++i)
        #pragma unroll
        for (int j = 0; j < 2; ++j)
            acc[i][j] = (f32x4){0.f, 0.f, 0.f, 0.f};

    for (int k0 = 0; k0 < F; k0 += 64) {
        #pragma unroll
        for (int h = 0; h < 2; ++h) {
            int gi = tid + h * 256;
            int m = gi >> 3, kg = gi & 7;
            uint4 va = {0u, 0u, 0u, 0u};
            int row = mT + m;
            if (row < M) va = *(const uint4*)(A + (size_t)row * F + k0 + kg * 8);
            *(uint4*)&As[m * 72 + kg * 8] = va;
            *(uint4*)&Ws[m * 72 + kg * 8] = *(const uint4*)(W + (size_t)m * F + k0 + kg * 8);
        }
        __syncthreads();
        #pragma unroll
        for (int S = 0; S < 2; ++S) {
            short8 af[2], bf[2];
            #pragma unroll
            for (int R = 0; R < 2; ++R)
                af[R] = *(const short8*)&As[(wr * 32 + R * 16 + r) * 72 + S * 32 + g * 8];
            #pragma unroll
            for (int C2 = 0; C2 < 2; ++C2)
                bf[C2] = *(const short8*)&Ws[(wcq * 32 + C2 * 16 + r) * 72 + S * 32 + g * 8];
            #pragma unroll
            for (int R = 0; R < 2; ++R)
                #pragma unroll
                for (int C2 = 0; C2 < 2; ++C2)
                    acc[R][C2] = __builtin_amdgcn_mfma_f32_16x16x32_bf16(af[R], bf[C2], acc[R][C2], 0, 0, 0);
        }
        __syncthreads();
    }
    #pragma unroll
    for (int R = 0; R < 2; ++R)
        #pragma unroll
        for (int C2 = 0; C2 < 2; ++C2)
            #pragma unroll
            for (int q = 0; q < 4; ++q) {
                int mm = mT + wr * 32 + R * 16 + g * 4 + q;
                int nn = wcq * 32 + C2 * 16 + r;
                if (mm < M && nn < NW)
                    out[(size_t)mm * OS + nn] = acc[R][C2][q];
            }
}

// ---------------------------------------------------------------------------
// d2 cc+gw GEMM writing batch-fastest transposed layouts:
//   CCT[p][f][b] (f<9), GWT[p][j][b][c] (n = 9+j*3+c); p = mm%1257, b = mm/1257
// ---------------------------------------------------------------------------
__global__ __launch_bounds__(256) void cc_gemmT(
    const u16* __restrict__ A, const u16* __restrict__ W,
    float* __restrict__ CCT, float* __restrict__ GWT, int M)
{
    __shared__ u16 As[64 * 72];
    __shared__ u16 Ws[64 * 72];
    int tid = threadIdx.x;
    int mT = blockIdx.x * 64;
    int wid = tid >> 6, lane = tid & 63;
    int wr = wid >> 1, wcq = wid & 1;
    int r = lane & 15, g = lane >> 4;
    f32x4 acc[2][2];
    #pragma unroll
    for (int i = 0; i < 2; ++i)
        #pragma unroll
        for (int j = 0; j < 2; ++j)
            acc[i][j] = (f32x4){0.f, 0.f, 0.f, 0.f};

    {
        #pragma unroll
        for (int h = 0; h < 2; ++h) {
            int gi = tid + h * 256;
            int m = gi >> 3, kg = gi & 7;
            uint4 va = {0u, 0u, 0u, 0u};
            int row = mT + m;
            if (row < M) va = *(const uint4*)(A + (size_t)row * 64 + kg * 8);
            *(uint4*)&As[m * 72 + kg * 8] = va;
            *(uint4*)&Ws[m * 72 + kg * 8] = *(const uint4*)(W + (size_t)m * 64 + kg * 8);
        }
        __syncthreads();
        #pragma unroll
        for (int S = 0; S < 2; ++S) {
            short8 af[2], bf[2];
            #pragma unroll
            for (int R = 0; R < 2; ++R)
                af[R] = *(const short8*)&As[(wr * 32 + R * 16 + r) * 72 + S * 32 + g * 8];
            #pragma unroll
            for (int C2 = 0; C2 < 2; ++C2)
                bf[C2] = *(const short8*)&Ws[(wcq * 32 + C2 * 16 + r) * 72 + S * 32 + g * 8];
            #pragma unroll
            for (int R = 0; R < 2; ++R)
                #pragma unroll
                for (int C2 = 0; C2 < 2; ++C2)
                    acc[R][C2] = __builtin_amdgcn_mfma_f32_16x16x32_bf16(af[R], bf[C2], acc[R][C2], 0, 0, 0);
        }
    }
    #pragma unroll
    for (int R = 0; R < 2; ++R)
        #pragma unroll
        for (int C2 = 0; C2 < 2; ++C2)
            #pragma unroll
            for (int q = 0; q < 4; ++q) {
                int mm = mT + wr * 32 + R * 16 + g * 4 + q;
                if (mm >= M) continue;
                int nn = wcq * 32 + C2 * 16 + r;
                if (nn >= 36) continue;
                int b = mm / 1257, p = mm - b * 1257;
                float val = acc[R][C2][q];
                if (nn < 9) {
                    CCT[((size_t)p * 9 + nn) * 32 + b] = val;
                } else {
                    int cj = nn - 9, j = cj / 3, c = cj - j * 3;
                    GWT[(size_t)p * 864 + j * 96 + b * 3 + c] = val;
                }
            }
}

// ---------------------------------------------------------------------------
// GEMM, LDS double-buffered (used for decoder G-GEMMs; shallow K, many blocks)
// ---------------------------------------------------------------------------
template<int ACT, int MASK>
__global__ __launch_bounds__(256) void lin_gemm(
    const u16* __restrict__ A, const u16* __restrict__ W,
    const float* __restrict__ bias, u16* __restrict__ Y,
    const int* __restrict__ maskT,
    int M, int K, int N, int P)
{
    __shared__ u16 As[2][64 * 72];
    __shared__ u16 Ws[2][64 * 72];
    int tid = threadIdx.x;
    int mT = blockIdx.x * 64, nT = blockIdx.y * 64;
    int wid = tid >> 6, lane = tid & 63;
    int wr = wid >> 1, wcq = wid & 1;
    int r = lane & 15, g = lane >> 4;
    int lm = tid >> 3, lkg = tid & 7;
    f32x4 acc[2][2];
    #pragma unroll
    for (int i = 0; i < 2; ++i)
        #pragma unroll
        for (int j = 0; j < 2; ++j)
            acc[i][j] = (f32x4){0.f, 0.f, 0.f, 0.f};

    uint4 ra[2], rw[2];
    #pragma unroll
    for (int h = 0; h < 2; ++h) {
        int m = lm + h * 32;
        int row = mT + m;
        uint4 z; z.x = z.y = z.z = z.w = 0u;
        ra[h] = (row < M) ? *(const uint4*)(A + (size_t)row * K + lkg * 8) : z;
        rw[h] = *(const uint4*)(W + (size_t)(nT + m) * K + lkg * 8);
    }
    #pragma unroll
    for (int h = 0; h < 2; ++h) {
        int m = lm + h * 32;
        *(uint4*)&As[0][m * 72 + lkg * 8] = ra[h];
        *(uint4*)&Ws[0][m * 72 + lkg * 8] = rw[h];
    }

    int cur = 0;
    for (int k0 = 0; k0 < K; k0 += 64) {
        __syncthreads();
        bool more = (k0 + 64 < K);
        if (more) {
            int kn = k0 + 64;
            #pragma unroll
            for (int h = 0; h < 2; ++h) {
                int m = lm + h * 32;
                int row = mT + m;
                uint4 z; z.x = z.y = z.z = z.w = 0u;
                ra[h] = (row < M) ? *(const uint4*)(A + (size_t)row * K + kn + lkg * 8) : z;
                rw[h] = *(const uint4*)(W + (size_t)(nT + m) * K + kn + lkg * 8);
            }
        }
        #pragma unroll
        for (int S = 0; S < 2; ++S) {
            short8 af[2], bf[2];
            #pragma unroll
            for (int R = 0; R < 2; ++R)
                af[R] = *(const short8*)&As[cur][(wr * 32 + R * 16 + r) * 72 + S * 32 + g * 8];
            #pragma unroll
            for (int C2 = 0; C2 < 2; ++C2)
                bf[C2] = *(const short8*)&Ws[cur][(wcq * 32 + C2 * 16 + r) * 72 + S * 32 + g * 8];
            #pragma unroll
            for (int R = 0; R < 2; ++R)
                #pragma unroll
                for (int C2 = 0; C2 < 2; ++C2)
                    acc[R][C2] = __builtin_amdgcn_mfma_f32_16x16x32_bf16(af[R], bf[C2], acc[R][C2], 0, 0, 0);
        }
        if (more) {
            #pragma unroll
            for (int h = 0; h < 2; ++h) {
                int m = lm + h * 32;
                *(uint4*)&As[cur ^ 1][m * 72 + lkg * 8] = ra[h];
                *(uint4*)&Ws[cur ^ 1][m * 72 + lkg * 8] = rw[h];
            }
        }
        cur ^= 1;
    }

    #pragma unroll
    for (int R = 0; R < 2; ++R)
        #pragma unroll
        for (int C2 = 0; C2 < 2; ++C2)
            #pragma unroll
            for (int q = 0; q < 4; ++q) {
                int mm = mT + wr * 32 + R * 16 + g * 4 + q;
                if (mm >= M) continue;
                int nn = nT + wcq * 32 + C2 * 16 + r;
                float v = acc[R][C2][q];
                if (bias) v += bias[nn];
                if (ACT == 1) v = v > 0.f ? v : expm1f(v);
                if (MASK) { if (maskT[mm % P] != 0) v = 0.f; }
                Y[(size_t)mm * N + nn] = f2b(v);
            }
}

// ---------------------------------------------------------------------------
// split-K GEMM: partials atomicAdd'ed into pre-zeroed f32 Yf.
// ---------------------------------------------------------------------------
__global__ __launch_bounds__(256) void lin_gemm_sk(
    const u16* __restrict__ A, const u16* __restrict__ W,
    float* __restrict__ Yf, int M, int K, int N, int KSTEPS)
{
    __shared__ u16 As[64 * 72];
    __shared__ u16 Ws[64 * 72];
    int tid = threadIdx.x;
    int mT = blockIdx.x * 64, nT = blockIdx.y * 64;
    int kbase = blockIdx.z * KSTEPS * 64;
    int wid = tid >> 6, lane = tid & 63;
    int wr = wid >> 1, wcq = wid & 1;
    int r = lane & 15, g = lane >> 4;
    f32x4 acc[2][2];
    #pragma unroll
    for (int i = 0; i < 2; ++i)
        #pragma unroll
        for (int j = 0; j < 2; ++j)
            acc[i][j] = (f32x4){0.f, 0.f, 0.f, 0.f};

    for (int s = 0; s < KSTEPS; ++s) {
        int k0 = kbase + s * 64;
        #pragma unroll
        for (int h = 0; h < 2; ++h) {
            int gi = tid + h * 256;
            int m = gi >> 3, kg = gi & 7;
            uint4 va = {0u, 0u, 0u, 0u};
            int row = mT + m;
            if (row < M) va = *(const uint4*)(A + (size_t)row * K + k0 + kg * 8);
            *(uint4*)&As[m * 72 + kg * 8] = va;
            *(uint4*)&Ws[m * 72 + kg * 8] = *(const uint4*)(W + (size_t)(nT + m) * K + k0 + kg * 8);
        }
        __syncthreads();
        #pragma unroll
        for (int S = 0; S < 2; ++S) {
            short8 af[2], bf[2];
            #pragma unroll
            for (int R = 0; R < 2; ++R)
                af[R] = *(const short8*)&As[(wr * 32 + R * 16 + r) * 72 + S * 32 + g * 8];
            #pragma unroll
            for (int C2 = 0; C2 < 2; ++C2)
                bf[C2] = *(const short8*)&Ws[(wcq * 32 + C2 * 16 + r) * 72 + S * 32 + g * 8];
            #pragma unroll
            for (int R = 0; R < 2; ++R)
                #pragma unroll
                for (int C2 = 0; C2 < 2; ++C2)
                    acc[R][C2] = __builtin_amdgcn_mfma_f32_16x16x32_bf16(af[R], bf[C2], acc[R][C2], 0, 0, 0);
        }
        __syncthreads();
    }
    #pragma unroll
    for (int R = 0; R < 2; ++R)
        #pragma unroll
        for (int C2 = 0; C2 < 2; ++C2)
            #pragma unroll
            for (int q = 0; q < 4; ++q) {
                int mm = mT + wr * 32 + R * 16 + g * 4 + q;
                if (mm >= M) continue;
                int nn = nT + wcq * 32 + C2 * 16 + r;
                atomicAdd(&Yf[(size_t)mm * N + nn], acc[R][C2][q]);
            }
}

// ---------------------------------------------------------------------------
// epilogue for split-K: bias + ELU + pad-mask + bf16 convert (4 elems/thread)
// ---------------------------------------------------------------------------
__global__ __launch_bounds__(256) void elu_mask_cvt(
    const float* __restrict__ Yf, const float* __restrict__ bias,
    const int* __restrict__ maskT, u16* __restrict__ Y,
    int M, int N, int P)
{
    int t = blockIdx.x * 256 + threadIdx.x;
    int tot = (M * N) >> 2;
    if (t >= tot) return;
    int e0 = t * 4;
    int m = e0 / N, n0 = e0 - m * N;
    float4 v = ((const float4*)Yf)[t];
    float o0 = v.x + bias[n0];
    float o1 = v.y + bias[n0 + 1];
    float o2 = v.z + bias[n0 + 2];
    float o3 = v.w + bias[n0 + 3];
    o0 = o0 > 0.f ? o0 : expm1f(o0);
    o1 = o1 > 0.f ? o1 : expm1f(o1);
    o2 = o2 > 0.f ? o2 : expm1f(o2);
    o3 = o3 > 0.f ? o3 : expm1f(o3);
    if (maskT[m % P] != 0) { o0 = 0.f; o1 = 0.f; o2 = 0.f; o3 = 0.f; }
    uint2 o;
    o.x = (u32)f2b(o0) | ((u32)f2b(o1) << 16);
    o.y = (u32)f2b(o2) | ((u32)f2b(o3) << 16);
    ((uint2*)Y)[t] = o;
}

// ---------------------------------------------------------------------------
// fce via split-K MFMA (f32 weights converted in-register)
// ---------------------------------------------------------------------------
__global__ __launch_bounds__(256) void fce_mfma(
    const u16* __restrict__ A, const float* __restrict__ Wf,
    const float* __restrict__ bias, float* __restrict__ z)
{
    __shared__ u16 As[32 * 72];
    __shared__ u16 Ws[64 * 72];
    int tid = threadIdx.x;
    int nT = blockIdx.x * 64;
    int kbase = blockIdx.y * 256;
    int wv = tid >> 6, lane = tid & 63;
    int r = lane & 15, g = lane >> 4;
    int m = tid >> 3, kg = tid & 7;
    f32x4 acc[2];
    acc[0] = (f32x4){0.f, 0.f, 0.f, 0.f};
    acc[1] = (f32x4){0.f, 0.f, 0.f, 0.f};

    for (int ks = 0; ks < 4; ++ks) {
        int k0 = kbase + ks * 64;
        *(uint4*)&As[m * 72 + kg * 8] = *(const uint4*)(A + (size_t)m * 20480 + k0 + kg * 8);
        #pragma unroll
        for (int h = 0; h < 2; ++h) {
            int row = m + h * 32;
            const float* wr2 = Wf + (size_t)(nT + row) * 20480 + k0 + kg * 8;
            float4 w0 = *(const float4*)(wr2);
            float4 w1 = *(const float4*)(wr2 + 4);
            u16 o[8] = { f2b(w0.x), f2b(w0.y), f2b(w0.z), f2b(w0.w),
                         f2b(w1.x), f2b(w1.y), f2b(w1.z), f2b(w1.w) };
            *(uint4*)&Ws[row * 72 + kg * 8] = *(const uint4*)o;
        }
        __syncthreads();
        #pragma unroll
        for (int S = 0; S < 2; ++S) {
            short8 bfr = *(const short8*)&Ws[(wv * 16 + r) * 72 + S * 32 + g * 8];
            #pragma unroll
            for (int R = 0; R < 2; ++R) {
                short8 af = *(const short8*)&As[(R * 16 + r) * 72 + S * 32 + g * 8];
                acc[R] = __builtin_amdgcn_mfma_f32_16x16x32_bf16(af, bfr, acc[R], 0, 0, 0);
            }
        }
        __syncthreads();
    }
    #pragma unroll
    for (int R = 0; R < 2; ++R)
        #pragma unroll
        for (int q = 0; q < 4; ++q) {
            int mm = R * 16 + g * 4 + q;
            int nn = nT + wv * 16 + r;
            float v = acc[R][q];
            if (blockIdx.y == 0) v += bias[nn];
            atomicAdd(&z[mm * 256 + nn], v);
        }
}

// ---------------------------------------------------------------------------
// fcd via MFMA (both operands f32 -> bf16 in-register)
// ---------------------------------------------------------------------------
__global__ __launch_bounds__(256) void fcd_mfma(
    const float* __restrict__ Af, const float* __restrict__ Wf,
    const float* __restrict__ bias, u16* __restrict__ Y)
{
    __shared__ u16 As[64 * 72];
    __shared__ u16 Ws[64 * 72];
    int tid = threadIdx.x;
    int nT = blockIdx.x * 64;
    int wid = tid >> 6, lane = tid & 63;
    int wr = wid >> 1, wcq = wid & 1;
    int r = lane & 15, g = lane >> 4;
    int m = tid >> 3, kg = tid & 7;
    f32x4 acc[2][2];
    #pragma unroll
    for (int i = 0; i < 2; ++i)
        #pragma unroll
        for (int j = 0; j < 2; ++j)
            acc[i][j] = (f32x4){0.f, 0.f, 0.f, 0.f};

    for (int k0 = 0; k0 < 256; k0 += 64) {
        {
            const float* ar = Af + (size_t)m * 256 + k0 + kg * 8;
            float4 a0 = *(const float4*)(ar);
            float4 a1 = *(const float4*)(ar + 4);
            u16 o[8] = { f2b(a0.x), f2b(a0.y), f2b(a0.z), f2b(a0.w),
                         f2b(a1.x), f2b(a1.y), f2b(a1.z), f2b(a1.w) };
            *(uint4*)&As[m * 72 + kg * 8] = *(const uint4*)o;
            uint4 z4; z4.x = z4.y = z4.z = z4.w = 0u;
            *(uint4*)&As[(m + 32) * 72 + kg * 8] = z4;
        }
        #pragma unroll
        for (int h = 0; h < 2; ++h) {
            int row = m + h * 32;
            const float* wr2 = Wf + (size_t)(nT + row) * 256 + k0 + kg * 8;
            float4 w0 = *(const float4*)(wr2);
            float4 w1 = *(const float4*)(wr2 + 4);
            u16 o[8] = { f2b(w0.x), f2b(w0.y), f2b(w0.z), f2b(w0.w),
                         f2b(w1.x), f2b(w1.y), f2b(w1.z), f2b(w1.w) };
            *(uint4*)&Ws[row * 72 + kg * 8] = *(const uint4*)o;
        }
        __syncthreads();
        #pragma unroll
        for (int S = 0; S < 2; ++S) {
            short8 af[2], bf[2];
            #pragma unroll
            for (int R = 0; R < 2; ++R)
                af[R] = *(const short8*)&As[(wr * 32 + R * 16 + r) * 72 + S * 32 + g * 8];
            #pragma unroll
            for (int C2 = 0; C2 < 2; ++C2)
                bf[C2] = *(const short8*)&Ws[(wcq * 32 + C2 * 16 + r) * 72 + S * 32 + g * 8];
            #pragma unroll
            for (int R = 0; R < 2; ++R)
                #pragma unroll
                for (int C2 = 0; C2 < 2; ++C2)
                    acc[R][C2] = __builtin_amdgcn_mfma_f32_16x16x32_bf16(af[R], bf[C2], acc[R][C2], 0, 0, 0);
        }
        __syncthreads();
    }
    #pragma unroll
    for (int R = 0; R < 2; ++R)
        #pragma unroll
        for (int C2 = 0; C2 < 2; ++C2)
            #pragma unroll
            for (int q = 0; q < 4; ++q) {
                int mm = wr * 32 + R * 16 + g * 4 + q;
                if (mm >= 32) continue;
                int nn = nT + wcq * 32 + C2 * 16 + r;
                float v = acc[R][C2][q] + bias[nn];
                Y[(size_t)mm * 20480 + nn] = f2b(v);
            }
}

// ---------------------------------------------------------------------------
// encoder feast agg (XCD-swizzled)
// ---------------------------------------------------------------------------
template<int F>
__global__ __launch_bounds__(256) void feast_agg(
    const u16* __restrict__ x, const float* __restrict__ cc,
    const int* __restrict__ nbrT, const float* __restrict__ bm,
    u16* __restrict__ agg, int Pin, int P, int Mtot)
{
    constexpr int FC = F / 64;
    __shared__ float s_p[4][81];
    __shared__ int s_nb[4][KN];
    int tid = threadIdx.x, wid = tid >> 6, lane = tid & 63;
    int row = xcd_swz(blockIdx.x, gridDim.x) * 4 + wid;
    bool aw = row < Mtot;
    int b = 0, p = 0;
    if (aw) { b = row / P; p = row - b * P; }
    if (aw && lane < KN) s_nb[wid][lane] = b * Pin + nbrT[p * 12 + lane];
    __syncthreads();

    if (aw && lane < KN) {
        int j = lane;
        const float* c0 = cc + (size_t)s_nb[wid][0] * 16;
        const float* cj = cc + (size_t)s_nb[wid][j] * 16;
        float L[KN];
        #pragma unroll
        for (int i = 0; i < KN; ++i) L[i] = bm[i] + cj[i] - c0[i];
        float mx = L[0];
        #pragma unroll
        for (int i = 1; i < KN; ++i) mx = fmaxf(mx, L[i]);
        float s = 0.f;
        #pragma unroll
        for (int i = 0; i < KN; ++i) { L[i] = __expf(L[i] - mx); s += L[i]; }
        float inv = 1.f / s;
        #pragma unroll
        for (int i = 0; i < KN; ++i) s_p[wid][i * KN + j] = L[i] * inv;
    }
    __syncthreads();

    if (aw) {
        float xn[KN][FC];
        #pragma unroll
        for (int i = 0; i < KN; ++i) {
            const u16* xr = x + (size_t)s_nb[wid][i] * F;
            #pragma unroll
            for (int c = 0; c < FC; ++c) xn[i][c] = b2f(xr[lane + c * 64]);
        }
        #pragma unroll
        for (int j = 0; j < KN; ++j) {
            float a[FC];
            #pragma unroll
            for (int c = 0; c < FC; ++c) a[c] = 0.f;
            #pragma unroll
            for (int i = 0; i < KN; ++i) {
                float pv = s_p[wid][i * KN + j];
                #pragma unroll
                for (int c = 0; c < FC; ++c) a[c] += xn[i][c] * pv;
            }
            u16* orow = agg + (size_t)row * (KN * F) + j * F;
            #pragma unroll
            for (int c = 0; c < FC; ++c) orow[lane + c * 64] = f2b(a[c]);
        }
    }
}

// ---------------------------------------------------------------------------
// decoder mix, 8-wide vectorized G reads, REGISTER-BOUNDED:
//   outer i-loop NOT unrolled (only 9 uint4 loads in flight) and
//   __launch_bounds__(256, 4) caps VGPR at 128.
// ---------------------------------------------------------------------------
template<int C>
__global__ __launch_bounds__(256, 4) void mix_feast_v(
    const u16* __restrict__ G, const float* __restrict__ cc,
    const int* __restrict__ nbrT, const float* __restrict__ bm,
    const float* __restrict__ bc, u16* __restrict__ y,
    int Pin, int P, int Mtot)
{
    constexpr int LPR = C / 8;          // lanes per row: 8 (C=64), 16 (C=128)
    constexpr int RPW = 64 / LPR;       // rows per wave: 8, 4
    constexpr int RPB = 4 * RPW;        // rows per block: 32, 16
    constexpr int GS = KN * C;
    __shared__ float s_p[RPB][84];
    __shared__ int   s_nb[RPB][KN];

    int tid = threadIdx.x, wid = tid >> 6, lane = tid & 63;
    int rowbase = xcd_swz(blockIdx.x, gridDim.x) * RPB;

    for (int t = tid; t < RPB * KN; t += 256) {
        int rr = t / KN, j = t - rr * KN;
        int row = rowbase + rr;
        int v = 0;
        if (row < Mtot) {
            int b = row / P, p = row - b * P;
            v = b * Pin + nbrT[p * 12 + j];
        }
        s_nb[rr][j] = v;
    }
    __syncthreads();

    // softmax columns
    {
        int rl, j0;
        if (C == 64) { rl = wid * RPW + (lane >> 3); j0 = lane & 7; }
        else         { rl = wid * RPW + (lane >> 4); j0 = lane & 15; }
        int row = rowbase + rl;
        if (row < Mtot && j0 <= KN) {
            float cc0[KN], bmr[KN];
            const float* c0 = cc + (size_t)s_nb[rl][0] * 16;
            #pragma unroll
            for (int i = 0; i < KN; ++i) { cc0[i] = c0[i]; bmr[i] = bm[i]; }
            int nj = 1;
            int jl[2]; jl[0] = j0; jl[1] = -1;
            if (C == 64 && j0 == 0) { jl[1] = 8; nj = 2; }
            if (j0 >= KN) nj = 0;
            for (int t = 0; t < nj; ++t) {
                int j = jl[t];
                const float* cj = cc + (size_t)s_nb[rl][j] * 16;
                float L[KN];
                #pragma unroll
                for (int i = 0; i < KN; ++i) L[i] = bmr[i] + cj[i] - cc0[i];
                float mx = L[0];
                #pragma unroll
                for (int i = 1; i < KN; ++i) mx = fmaxf(mx, L[i]);
                float sm = 0.f;
                #pragma unroll
                for (int i = 0; i < KN; ++i) { L[i] = __expf(L[i] - mx); sm += L[i]; }
                float inv = 1.f / sm;
                #pragma unroll
                for (int i = 0; i < KN; ++i) s_p[rl][i * KN + j] = L[i] * inv;
            }
        }
    }
    __syncthreads();

    // mix: each lane = 8 channels of one row; i-loop kept rolled to bound
    // the number of in-flight uint4 loads (9 per iteration).
    {
        int rl = wid * RPW + lane / LPR;
        int coff = (lane % LPR) * 8;
        int row = rowbase + rl;
        if (row >= Mtot) return;
        int b = row / P, p = row - b * P;
        (void)b;
        float acc[8];
        #pragma unroll
        for (int k = 0; k < 8; ++k) acc[k] = bc[coff + k];
        #pragma unroll 1
        for (int i = 0; i < KN; ++i) {
            const u16* gr = G + (size_t)s_nb[rl][i] * GS + coff;
            #pragma unroll
            for (int j = 0; j < KN; ++j) {
                uint4 gv = *(const uint4*)(gr + j * C);
                const u16* ge = (const u16*)&gv;
                float p0 = s_p[rl][i * KN + j];
                #pragma unroll
                for (int k = 0; k < 8; ++k) acc[k] += p0 * b2f(ge[k]);
            }
        }
        u16 o[8];
        #pragma unroll
        for (int k = 0; k < 8; ++k) {
            float v = acc[k];
            v = v > 0.f ? v : expm1f(v);
            if (p == P - 1) v = 0.f;
            o[k] = f2b(v);
        }
        *(uint4*)(y + (size_t)row * C + coff) = *(const uint4*)o;
    }
}

// ---------------------------------------------------------------------------
// e0 fused feast (F=3 -> C=64), XCD-swizzled
// ---------------------------------------------------------------------------
__global__ __launch_bounds__(256) void feast_e0(
    const float* __restrict__ x, const int* __restrict__ nbr,
    const int* __restrict__ sel,
    const float* __restrict__ wm, const float* __restrict__ bm,
    const float* __restrict__ wcw, const float* __restrict__ bc,
    u16* __restrict__ y,
    int Nin, int P, int Nlevel, int Mtot)
{
    constexpr int F = 3, C = 64, FS = 4, Q = 27;
    __shared__ float s_wm[KN * FS];
    __shared__ float s_wc[C * Q];
    __shared__ float s_bm[KN];
    __shared__ float s_xn[4][KN * FS];
    __shared__ float s_lg[4][81];
    __shared__ float s_pm[4][81];
    __shared__ float s_ag[4][Q];
    __shared__ int   s_idx[4][KN];

    int tid = threadIdx.x, wid = tid >> 6, lane = tid & 63;
    for (int t = tid; t < KN * F; t += 256) { int i = t / F, f = t - i * F; s_wm[i * FS + f] = wm[t]; }
    for (int t = tid; t < C * Q; t += 256) s_wc[t] = wcw[t];
    if (tid < KN) s_bm[tid] = bm[tid];

    int wg = xcd_swz(blockIdx.x, gridDim.x) * 4 + wid;
    bool aw = wg < Mtot;
    int b = 0, p = 0, n = 0;
    if (aw) {
        b = wg / P; p = wg - b * P;
        n = sel[p];
    }
    if (aw && lane < KN) s_idx[wid][lane] = nbr[n * KN + lane];
    __syncthreads();

    if (aw) {
        const float* xb = x + (size_t)b * Nin * F;
        for (int t = lane; t < KN * F; t += 64) {
            int i = t / F, f = t - i * F;
            s_xn[wid][i * FS + f] = xb[(size_t)s_idx[wid][i] * F + f];
        }
    }
    __syncthreads();

    if (aw) {
        for (int pr = lane; pr < 81; pr += 64) {
            int i = pr / KN, j = pr - i * KN;
            float acc = s_bm[i];
            for (int f = 0; f < F; ++f)
                acc += (s_xn[wid][j * FS + f] - s_xn[wid][f]) * s_wm[i * FS + f];
            s_lg[wid][pr] = acc;
        }
    }
    __syncthreads();

    if (aw && lane < KN) {
        int j = lane;
        float mx = -1e30f;
        #pragma unroll
        for (int i = 0; i < KN; ++i) mx = fmaxf(mx, s_lg[wid][i * KN + j]);
        float sm = 0.f, ev[KN];
        #pragma unroll
        for (int i = 0; i < KN; ++i) { ev[i] = __expf(s_lg[wid][i * KN + j] - mx); sm += ev[i]; }
        float inv = 1.f / sm;
        #pragma unroll
        for (int i = 0; i < KN; ++i) s_pm[wid][i * KN + j] = ev[i] * inv;
    }
    __syncthreads();

    if (aw) {
        for (int t = lane; t < Q; t += 64) {
            int f = t / KN, j = t - f * KN;
            float acc = 0.f;
            #pragma unroll
            for (int i = 0; i < KN; ++i) acc += s_xn[wid][i * FS + f] * s_pm[wid][i * KN + j];
            s_ag[wid][t] = acc;
        }
    }
    __syncthreads();

    if (aw) {
        int c = lane;
        float acc = 0.f;
        #pragma unroll
        for (int q = 0; q < Q; ++q)
            acc += s_wc[c * Q + q] * s_ag[wid][q];
        float val = acc + bc[c];
        val = val > 0.f ? val : expm1f(val);
        if (n == Nlevel - 1) val = 0.f;
        y[(size_t)wg * C + c] = f2b(val);
    }
}

// ---------------------------------------------------------------------------
// d2 mix, batch-coalesced: lane = batch, wave = 2 vertices x 32 batches.
// ---------------------------------------------------------------------------
__global__ __launch_bounds__(256) void mix_d2t(
    const float* __restrict__ CCT, const float* __restrict__ GWT,
    const int* __restrict__ nbrT,
    const float* __restrict__ bm9, const float* __restrict__ bc3,
    float* __restrict__ out)
{
    __shared__ float s_out[8][32][3];
    int tid = threadIdx.x, wid = tid >> 6, lane = tid & 63;
    int sub = lane >> 5, b = lane & 31;
    int vbase = xcd_swz(blockIdx.x, gridDim.x) * 8;
    int v = vbase + wid * 2 + sub;

    int nbi[KN];
    #pragma unroll
    for (int i = 0; i < KN; ++i) nbi[i] = nbrT[v * 12 + i];
    float bmr[KN];
    #pragma unroll
    for (int i = 0; i < KN; ++i) bmr[i] = bm9[i];

    float cc0[KN];
    {
        const float* c0 = CCT + (size_t)nbi[0] * 9 * 32 + b;
        #pragma unroll
        for (int f = 0; f < KN; ++f) cc0[f] = c0[f * 32];
    }
    float a0 = bc3[0], a1 = bc3[1], a2 = bc3[2];
    #pragma unroll
    for (int j = 0; j < KN; ++j) {
        const float* cj = CCT + (size_t)nbi[j] * 9 * 32 + b;
        float L[KN];
        #pragma unroll
        for (int i = 0; i < KN; ++i) L[i] = bmr[i] + cj[i * 32] - cc0[i];
        float mx = L[0];
        #pragma unroll
        for (int i = 1; i < KN; ++i) mx = fmaxf(mx, L[i]);
        float sm = 0.f;
        #pragma unroll
        for (int i = 0; i < KN; ++i) { L[i] = __expf(L[i] - mx); sm += L[i]; }
        float inv = 1.f / sm;
        #pragma unroll
        for (int i = 0; i < KN; ++i) {
            float pv = L[i] * inv;
            const float* g = GWT + (size_t)nbi[i] * 864 + j * 96 + b * 3;
            a0 += pv * g[0];
            a1 += pv * g[1];
            a2 += pv * g[2];
        }
    }
    if (v == 5023) { a0 = 0.f; a1 = 0.f; a2 = 0.f; }
    s_out[wid * 2 + sub][b][0] = a0;
    s_out[wid * 2 + sub][b][1] = a1;
    s_out[wid * 2 + sub][b][2] = a2;
    __syncthreads();
    {
        int bb = tid >> 3, vi = tid & 7;
        float* dst = out + ((size_t)bb * 5024 + vbase + vi) * 3;
        dst[0] = s_out[vi][bb][0];
        dst[1] = s_out[vi][bb][1];
        dst[2] = s_out[vi][bb][2];
    }
}

// ---------------------------------------------------------------------------
extern "C" void kernel_launch(void* const* d_in, const int* in_sizes, int n_in,
                              void* d_out, int out_size, void* d_ws, size_t ws_size,
                              hipStream_t stream)
{
    const float* x     = (const float*)d_in[0];
    const int*   nbr0  = (const int*)d_in[1];
    const int*   nbr1  = (const int*)d_in[2];
    const int*   nbr2  = (const int*)d_in[3];
    const float* D0    = (const float*)d_in[4];
    const float* U0    = (const float*)d_in[5];
    const float* D1    = (const float*)d_in[6];
    const float* U1    = (const float*)d_in[7];
    const float* D2    = (const float*)d_in[8];
    const float* U2    = (const float*)d_in[9];
    const float* e0_wm = (const float*)d_in[10]; const float* e0_bm = (const float*)d_in[11];
    const float* e0_wc = (const float*)d_in[12]; const float* e0_bc = (const float*)d_in[13];
    const float* e1_wm = (const float*)d_in[14]; const float* e1_bm = (const float*)d_in[15];
    const float* e1_wc = (const float*)d_in[16]; const float* e1_bc = (const float*)d_in[17];
    const float* e2_wm = (const float*)d_in[18]; const float* e2_bm = (const float*)d_in[19];
    const float* e2_wc = (const float*)d_in[20]; const float* e2_bc = (const float*)d_in[21];
    const float* fce_w = (const float*)d_in[22]; const float* fce_b = (const float*)d_in[23];
    const float* fcd_w = (const float*)d_in[24]; const float* fcd_b = (const float*)d_in[25];
    const float* d0_wm = (const float*)d_in[26]; const float* d0_bm = (const float*)d_in[27];
    const float* d0_wc = (const float*)d_in[28]; const float* d0_bc = (const float*)d_in[29];
    const float* d1_wm = (const float*)d_in[30]; const float* d1_bm = (const float*)d_in[31];
    const float* d1_wc = (const float*)d_in[32]; const float* d1_bc = (const float*)d_in[33];
    const float* d2_wm = (const float*)d_in[34]; const float* d2_bm = (const float*)d_in[35];
    const float* d2_wc = (const float*)d_in[36]; const float* d2_bc = (const float*)d_in[37];

    char* w = (char*)d_ws;
    int* idxD0 = (int*)(w);
    int* idxD1 = idxD0 + 1257;
    int* idxD2 = idxD1 + 315;
    int* idxU0 = idxD2 + 80;
    int* idxU1 = idxU0 + 5024;
    int* idxU2 = idxU1 + 1257;
    int* nbrD1  = (int*)(w + 33024);
    int* nbrD2  = (int*)(w + 48144);
    int* nbrU2  = (int*)(w + 51984);
    int* nbrU1  = (int*)(w + 67104);
    int* nbrU0  = (int*)(w + 127440);
    int* maskE1 = (int*)(w + 368640);
    int* maskE2 = (int*)(w + 369920);
    u16* wcrE1 = (u16*)(w + 370432);
    u16* wcrE2 = (u16*)(w + 517888);
    u16* wg0   = (u16*)(w + 1107712);
    u16* wg1   = (u16*)(w + 1697536);
    u16* ccwE1 = (u16*)(w + 1844992);
    u16* ccwE2 = (u16*)(w + 1853184);
    u16* ccwD0 = (u16*)(w + 1869568);
    u16* ccwD1 = (u16*)(w + 1902336);
    u16* w3    = (u16*)(w + 1918720);
    float* zbuf = (float*)(w + 1926912);

    u16*   X1   = (u16*)  (w + 2097152);
    float* CC1  = (float*)(w + 7245824);
    u16*   AGG1 = (u16*)  (w + 9820160);
    u16*   X2   = (u16*)  (w + 21432320);
    float* CC2  = (float*)(w + 24012800);
    u16*   AGG2 = (u16*)  (w + 24657920);
    u16*   X3   = (u16*)  (w + 2097152);
    u16*   X3P  = (u16*)  (w + 3407872);
    float* CCD0 = (float*)(w + 4718592);
    u16*   G0   = (u16*)  (w + 4882432);
    u16*   XD1P = (u16*)  (w + 10780672);
    float* CCD1 = (float*)(w + 13361152);
    u16*   G1   = (u16*)  (w + 14006272);
    u16*   XD2P = (u16*)  (w + 25618432);
    float* CCT  = (float*)(w + 30767104);
    float* GWT  = (float*)(w + 32215168);
    float* X2F  = (float*)(w + 36559360);
    float* X3F  = (float*)(w + 41720320);

    // prep
    extract_idx_all<<<8248, 256, 0, stream>>>(D0, D1, D2, U0, U1, U2,
                                              idxD0, idxD1, idxD2, idxU0, idxU1, idxU2);
    cvt_weights<<<3072, 256, 0, stream>>>(e1_wc, e2_wc, d0_wc, d1_wc,
                                          e1_wm, e2_wm, d0_wm, d1_wm, d2_wm, d2_wc,
                                          wcrE1, wcrE2, wg0, wg1,
                                          ccwE1, ccwE2, ccwD0, ccwD1, w3, zbuf);
    compose_tables<<<248, 256, 0, stream>>>(nbr0, nbr1, nbr2,
                                            idxD1, idxD2, idxU0, idxU1, idxU2,
                                            nbrD1, nbrD2, nbrU2, nbrU1, nbrU0,
                                            maskE1, maskE2);
    zero_f32<<<1900, 256, 0, stream>>>((float4*)X2F, 486400);   // X2F + X3F (adjacent)

    // ---- encoder ----
    feast_e0<<<10056, 256, 0, stream>>>(x, nbr0, idxD0, e0_wm, e0_bm, e0_wc, e0_bc,
                                        X1, 5024, 1257, 5024, 40224);
    cc_gemm<16, 16><<<629, 256, 0, stream>>>(X1, ccwE1, CC1, 40224, 64);
    feast_agg<64><<<2520, 256, 0, stream>>>(X1, CC1, nbrD1, e1_bm, AGG1, 1257, 315, 10080);
    lin_gemm_sk<<<dim3(158, 2, 3), 256, 0, stream>>>(AGG1, wcrE1, X2F, 10080, 576, 128, 3);
    elu_mask_cvt<<<1260, 256, 0, stream>>>(X2F, e1_bc, maskE1, X2, 10080, 128, 315);
    cc_gemm<16, 16><<<158, 256, 0, stream>>>(X2, ccwE2, CC2, 10080, 128);
    feast_agg<128><<<640, 256, 0, stream>>>(X2, CC2, nbrD2, e2_bm, AGG2, 315, 80, 2560);
    lin_gemm_sk<<<dim3(40, 4, 6), 256, 0, stream>>>(AGG2, wcrE2, X3F, 2560, 1152, 256, 3);
    elu_mask_cvt<<<640, 256, 0, stream>>>(X3F, e2_bc, maskE2, X3, 2560, 256, 80);

    // ---- bottleneck ----
    fce_mfma<<<dim3(4, 80), 256, 0, stream>>>(X3, fce_w, fce_b, zbuf);
    fcd_mfma<<<320, 256, 0, stream>>>(zbuf, fcd_w, fcd_b, X3P);

    // ---- decoder ----
    cc_gemm<16, 16><<<40, 256, 0, stream>>>(X3P, ccwD0, CCD0, 2560, 256);
    lin_gemm<0, 0><<<dim3(40, 18), 256, 0, stream>>>(X3P, wg0, nullptr, G0, nullptr,
                                                     2560, 256, 1152, 1);
    mix_feast_v<128><<<630, 256, 0, stream>>>(G0, CCD0, nbrU2, d0_bm, d0_bc, XD1P,
                                              80, 315, 10080);
    cc_gemm<16, 16><<<158, 256, 0, stream>>>(XD1P, ccwD1, CCD1, 10080, 128);
    lin_gemm<0, 0><<<dim3(158, 9), 256, 0, stream>>>(XD1P, wg1, nullptr, G1, nullptr,
                                                     10080, 128, 576, 1);
    mix_feast_v<64><<<1257, 256, 0, stream>>>(G1, CCD1, nbrU1, d1_bm, d1_bc, XD2P,
                                              315, 1257, 40224);
    cc_gemmT<<<629, 256, 0, stream>>>(XD2P, w3, CCT, GWT, 40224);
    mix_d2t<<<628, 256, 0, stream>>>(CCT, GWT, nbrU0, d2_bm, d2_bc, (float*)d_out);
}

// Round 15
// 232.648 us; speedup vs baseline: 1.1018x; 1.0130x over previous
//
#include <hip/hip_runtime.h>
#include <cstddef>

#define KN 9
typedef unsigned short u16;
typedef unsigned int u32;
typedef __attribute__((ext_vector_type(8))) short short8;
typedef __attribute__((ext_vector_type(4))) float f32x4;

__device__ inline u16 f2b(float f) {
    union { float f; u32 u; } v; v.f = f;
    u32 r = v.u + 0x7FFFu + ((v.u >> 16) & 1u);
    return (u16)(r >> 16);
}
__device__ inline float b2f(u16 h) {
    union { u32 u; float f; } v; v.u = ((u32)h) << 16; return v.f;
}

// bijective XCD-aware block swizzle (m204)
__device__ inline int xcd_swz(int bid, int n) {
    int q = n >> 3, r = n & 7;
    int x = bid & 7, pos = bid >> 3;
    return (x < r ? x * (q + 1) : r * (q + 1) + (x - r) * q) + pos;
}

// ---------------------------------------------------------------------------
// all 6 one-hot pool matrices -> gather indices
// ---------------------------------------------------------------------------
__global__ void extract_idx_all(
    const float* __restrict__ D0, const float* __restrict__ D1, const float* __restrict__ D2,
    const float* __restrict__ U0, const float* __restrict__ U1, const float* __restrict__ U2,
    int* __restrict__ iD0, int* __restrict__ iD1, int* __restrict__ iD2,
    int* __restrict__ iU0, int* __restrict__ iU1, int* __restrict__ iU2)
{
    int blk = blockIdx.x;
    const float* L; int M; int* out; int p;
    if      (blk < 1257) { L = D0; M = 5024; out = iD0; p = blk; }
    else if (blk < 1572) { L = D1; M = 1257; out = iD1; p = blk - 1257; }
    else if (blk < 1652) { L = D2; M = 315;  out = iD2; p = blk - 1572; }
    else if (blk < 6676) { L = U0; M = 1257; out = iU0; p = blk - 1652; }
    else if (blk < 7933) { L = U1; M = 315;  out = iU1; p = blk - 6676; }
    else                 { L = U2; M = 80;   out = iU2; p = blk - 7933; }
    const float* row = L + (size_t)p * M;
    for (int m = threadIdx.x; m < M; m += 256)
        if (row[m] > 0.5f) out[p] = m;
}

// ---------------------------------------------------------------------------
// zero f32 region (for split-K atomic accumulation), per launch
// ---------------------------------------------------------------------------
__global__ void zero_f32(float4* __restrict__ p, int n4)
{
    int t = blockIdx.x * 256 + threadIdx.x;
    if (t < n4) p[t] = (float4){0.f, 0.f, 0.f, 0.f};
}

// ---------------------------------------------------------------------------
// transpose x [32][5024][3] f32 -> XT [5024][32][3] f32
// ---------------------------------------------------------------------------
__global__ void xpose_x(const float* __restrict__ x, float* __restrict__ xt)
{
    int t = blockIdx.x * 256 + threadIdx.x;
    if (t >= 482304) return;                 // 32*5024*3
    int f = t % 3; int rem = t / 3;
    int n = rem % 5024; int b = rem / 5024;
    xt[((size_t)n * 32 + b) * 3 + f] = x[t];
}

// ---------------------------------------------------------------------------
// weight conversions + zbuf zeroing
// ---------------------------------------------------------------------------
__device__ inline void wcr_one(const float* __restrict__ wc, u16* __restrict__ out, int t, int F) {
    int FK = F * KN;
    int c = t / FK, rem = t - c * FK, j = rem / F, f = rem - j * F;
    out[t] = f2b(wc[(size_t)c * FK + f * KN + j]);
}
__device__ inline void wg_one(const float* __restrict__ wc, u16* __restrict__ out, int t, int F, int C) {
    int n = t / F, f = t - n * F;
    int j = n / C, c = n - j * C;
    out[t] = f2b(wc[(size_t)c * (F * KN) + f * KN + j]);
}
__device__ inline void ccw_one(const float* __restrict__ wm, u16* __restrict__ out, int t, int F) {
    int n = t / F, f = t - n * F;
    out[t] = (n < KN) ? f2b(wm[n * F + f]) : (u16)0;
}
__global__ void cvt_weights(
    const float* __restrict__ e1_wc, const float* __restrict__ e2_wc,
    const float* __restrict__ d0_wc, const float* __restrict__ d1_wc,
    const float* __restrict__ e1_wm, const float* __restrict__ e2_wm,
    const float* __restrict__ d0_wm, const float* __restrict__ d1_wm,
    const float* __restrict__ d2_wm, const float* __restrict__ d2_wc,
    u16* __restrict__ wcrE1, u16* __restrict__ wcrE2,
    u16* __restrict__ wg0, u16* __restrict__ wg1,
    u16* __restrict__ ccwE1, u16* __restrict__ ccwE2,
    u16* __restrict__ ccwD0, u16* __restrict__ ccwD1,
    u16* __restrict__ w3, float* __restrict__ zbuf)
{
    int t = blockIdx.x * 256 + threadIdx.x;
    if (t < 73728)  { wcr_one(e1_wc, wcrE1, t, 64);       return; } t -= 73728;
    if (t < 294912) { wcr_one(e2_wc, wcrE2, t, 128);      return; } t -= 294912;
    if (t < 294912) { wg_one(d0_wc, wg0, t, 256, 128);    return; } t -= 294912;
    if (t < 73728)  { wg_one(d1_wc, wg1, t, 128, 64);     return; } t -= 73728;
    if (t < 4096)   { ccw_one(e1_wm, ccwE1, t, 64);       return; } t -= 4096;
    if (t < 8192)   { ccw_one(e2_wm, ccwE2, t, 128);      return; } t -= 8192;
    if (t < 16384)  { ccw_one(d0_wm, ccwD0, t, 256);      return; } t -= 16384;
    if (t < 8192)   { ccw_one(d1_wm, ccwD1, t, 128);      return; } t -= 8192;
    if (t < 4096) {
        int n = t >> 6, k = t & 63;
        float v = 0.f;
        if (n < KN) v = d2_wm[n * 64 + k];
        else if (n >= 9 && n < 36) {
            int cj = n - 9, j = cj / 3, c = cj - j * 3;     // j-major
            v = d2_wc[(size_t)c * 576 + k * KN + j];
        }
        w3[t] = f2b(v);
        return;
    } t -= 4096;
    if (t < 8192) zbuf[t] = 0.f;
}

// ---------------------------------------------------------------------------
// composed neighbor tables (stride 12) + encoder pad masks
// ---------------------------------------------------------------------------
__global__ void compose_tables(
    const int* __restrict__ nbr0, const int* __restrict__ nbr1, const int* __restrict__ nbr2,
    const int* __restrict__ idxD1, const int* __restrict__ idxD2,
    const int* __restrict__ idxU0, const int* __restrict__ idxU1, const int* __restrict__ idxU2,
    int* __restrict__ nbrD1, int* __restrict__ nbrD2,
    int* __restrict__ nbrU2, int* __restrict__ nbrU1, int* __restrict__ nbrU0,
    int* __restrict__ maskE1, int* __restrict__ maskE2)
{
    int t = blockIdx.x * 256 + threadIdx.x;
    if (t < 2835)  { int p = t / 9, j = t - p * 9; nbrD1[p * 12 + j] = nbr1[idxD1[p] * 9 + j]; return; } t -= 2835;
    if (t < 720)   { int p = t / 9, j = t - p * 9; nbrD2[p * 12 + j] = nbr2[idxD2[p] * 9 + j]; return; } t -= 720;
    if (t < 2835)  { int p = t / 9, j = t - p * 9; nbrU2[p * 12 + j] = idxU2[nbr2[p * 9 + j]]; return; } t -= 2835;
    if (t < 11313) { int p = t / 9, j = t - p * 9; nbrU1[p * 12 + j] = idxU1[nbr1[p * 9 + j]]; return; } t -= 11313;
    if (t < 45216) { int p = t / 9, j = t - p * 9; nbrU0[p * 12 + j] = idxU0[nbr0[p * 9 + j]]; return; } t -= 45216;
    if (t < 315)   { maskE1[t] = (idxD1[t] == 1256) ? 1 : 0; return; } t -= 315;
    if (t < 80)    { maskE2[t] = (idxD2[t] == 314) ? 1 : 0; }
}

// ---------------------------------------------------------------------------
// cc GEMM: out[m][nn<NW] = sum_f A[m][f]*W[nn][f]   (f32 out, row stride OS)
// ---------------------------------------------------------------------------
template<int NW, int OS>
__global__ __launch_bounds__(256) void cc_gemm(
    const u16* __restrict__ A, const u16* __restrict__ W,
    float* __restrict__ out, int M, int F)
{
    __shared__ u16 As[64 * 72];
    __shared__ u16 Ws[64 * 72];
    int tid = threadIdx.x;
    int mT = blockIdx.x * 64;
    int wid = tid >> 6, lane = tid & 63;
    int wr = wid >> 1, wcq = wid & 1;
    int r = lane & 15, g = lane >> 4;
    f32x4 acc[2][2];
    #pragma unroll
    for (int i = 0; i < 2; ++i)
        #pragma unroll
        for (int j = 0; j < 2; ++j)
            acc[i][j] = (f32x4){0.f, 0.f, 0.f, 0.f};

    for (int k0 = 0; k0 < F; k0 += 64) {
        #pragma unroll
        for (int h = 0; h < 2; ++h) {
            int gi = tid + h * 256;
            int m = gi >> 3, kg = gi & 7;
            uint4 va = {0u, 0u, 0u, 0u};
            int row = mT + m;
            if (row < M) va = *(const uint4*)(A + (size_t)row * F + k0 + kg * 8);
            *(uint4*)&As[m * 72 + kg * 8] = va;
            *(uint4*)&Ws[m * 72 + kg * 8] = *(const uint4*)(W + (size_t)m * F + k0 + kg * 8);
        }
        __syncthreads();
        #pragma unroll
        for (int S = 0; S < 2; ++S) {
            short8 af[2], bf[2];
            #pragma unroll
            for (int R = 0; R < 2; ++R)
                af[R] = *(const short8*)&As[(wr * 32 + R * 16 + r) * 72 + S * 32 + g * 8];
            #pragma unroll
            for (int C2 = 0; C2 < 2; ++C2)
                bf[C2] = *(const short8*)&Ws[(wcq * 32 + C2 * 16 + r) * 72 + S * 32 + g * 8];
            #pragma unroll
            for (int R = 0; R < 2; ++R)
                #pragma unroll
                for (int C2 = 0; C2 < 2; ++C2)
                    acc[R][C2] = __builtin_amdgcn_mfma_f32_16x16x32_bf16(af[R], bf[C2], acc[R][C2], 0, 0, 0);
        }
        __syncthreads();
    }
    #pragma unroll
    for (int R = 0; R < 2; ++R)
        #pragma unroll
        for (int C2 = 0; C2 < 2; ++C2)
            #pragma unroll
            for (int q = 0; q < 4; ++q) {
                int mm = mT + wr * 32 + R * 16 + g * 4 + q;
                int nn = wcq * 32 + C2 * 16 + r;
                if (mm < M && nn < NW)
                    out[(size_t)mm * OS + nn] = acc[R][C2][q];
            }
}

// ---------------------------------------------------------------------------
// d2 cc+gw GEMM writing batch-fastest transposed layouts:
//   CCT[p][f][b] (f<9), GWT[p][j][b][c] (n = 9+j*3+c); p = mm%1257, b = mm/1257
// ---------------------------------------------------------------------------
__global__ __launch_bounds__(256) void cc_gemmT(
    const u16* __restrict__ A, const u16* __restrict__ W,
    float* __restrict__ CCT, float* __restrict__ GWT, int M)
{
    __shared__ u16 As[64 * 72];
    __shared__ u16 Ws[64 * 72];
    int tid = threadIdx.x;
    int mT = blockIdx.x * 64;
    int wid = tid >> 6, lane = tid & 63;
    int wr = wid >> 1, wcq = wid & 1;
    int r = lane & 15, g = lane >> 4;
    f32x4 acc[2][2];
    #pragma unroll
    for (int i = 0; i < 2; ++i)
        #pragma unroll
        for (int j = 0; j < 2; ++j)
            acc[i][j] = (f32x4){0.f, 0.f, 0.f, 0.f};

    {
        #pragma unroll
        for (int h = 0; h < 2; ++h) {
            int gi = tid + h * 256;
            int m = gi >> 3, kg = gi & 7;
            uint4 va = {0u, 0u, 0u, 0u};
            int row = mT + m;
            if (row < M) va = *(const uint4*)(A + (size_t)row * 64 + kg * 8);
            *(uint4*)&As[m * 72 + kg * 8] = va;
            *(uint4*)&Ws[m * 72 + kg * 8] = *(const uint4*)(W + (size_t)m * 64 + kg * 8);
        }
        __syncthreads();
        #pragma unroll
        for (int S = 0; S < 2; ++S) {
            short8 af[2], bf[2];
            #pragma unroll
            for (int R = 0; R < 2; ++R)
                af[R] = *(const short8*)&As[(wr * 32 + R * 16 + r) * 72 + S * 32 + g * 8];
            #pragma unroll
            for (int C2 = 0; C2 < 2; ++C2)
                bf[C2] = *(const short8*)&Ws[(wcq * 32 + C2 * 16 + r) * 72 + S * 32 + g * 8];
            #pragma unroll
            for (int R = 0; R < 2; ++R)
                #pragma unroll
                for (int C2 = 0; C2 < 2; ++C2)
                    acc[R][C2] = __builtin_amdgcn_mfma_f32_16x16x32_bf16(af[R], bf[C2], acc[R][C2], 0, 0, 0);
        }
    }
    #pragma unroll
    for (int R = 0; R < 2; ++R)
        #pragma unroll
        for (int C2 = 0; C2 < 2; ++C2)
            #pragma unroll
            for (int q = 0; q < 4; ++q) {
                int mm = mT + wr * 32 + R * 16 + g * 4 + q;
                if (mm >= M) continue;
                int nn = wcq * 32 + C2 * 16 + r;
                if (nn >= 36) continue;
                int b = mm / 1257, p = mm - b * 1257;
                float val = acc[R][C2][q];
                if (nn < 9) {
                    CCT[((size_t)p * 9 + nn) * 32 + b] = val;
                } else {
                    int cj = nn - 9, j = cj / 3, c = cj - j * 3;
                    GWT[(size_t)p * 864 + j * 96 + b * 3 + c] = val;
                }
            }
}

// ---------------------------------------------------------------------------
// GEMM, LDS double-buffered (used for decoder G-GEMMs; shallow K, many blocks)
// ---------------------------------------------------------------------------
template<int ACT, int MASK>
__global__ __launch_bounds__(256) void lin_gemm(
    const u16* __restrict__ A, const u16* __restrict__ W,
    const float* __restrict__ bias, u16* __restrict__ Y,
    const int* __restrict__ maskT,
    int M, int K, int N, int P)
{
    __shared__ u16 As[2][64 * 72];
    __shared__ u16 Ws[2][64 * 72];
    int tid = threadIdx.x;
    int mT = blockIdx.x * 64, nT = blockIdx.y * 64;
    int wid = tid >> 6, lane = tid & 63;
    int wr = wid >> 1, wcq = wid & 1;
    int r = lane & 15, g = lane >> 4;
    int lm = tid >> 3, lkg = tid & 7;
    f32x4 acc[2][2];
    #pragma unroll
    for (int i = 0; i < 2; ++i)
        #pragma unroll
        for (int j = 0; j < 2; ++j)
            acc[i][j] = (f32x4){0.f, 0.f, 0.f, 0.f};

    uint4 ra[2], rw[2];
    #pragma unroll
    for (int h = 0; h < 2; ++h) {
        int m = lm + h * 32;
        int row = mT + m;
        uint4 z; z.x = z.y = z.z = z.w = 0u;
        ra[h] = (row < M) ? *(const uint4*)(A + (size_t)row * K + lkg * 8) : z;
        rw[h] = *(const uint4*)(W + (size_t)(nT + m) * K + lkg * 8);
    }
    #pragma unroll
    for (int h = 0; h < 2; ++h) {
        int m = lm + h * 32;
        *(uint4*)&As[0][m * 72 + lkg * 8] = ra[h];
        *(uint4*)&Ws[0][m * 72 + lkg * 8] = rw[h];
    }

    int cur = 0;
    for (int k0 = 0; k0 < K; k0 += 64) {
        __syncthreads();
        bool more = (k0 + 64 < K);
        if (more) {
            int kn = k0 + 64;
            #pragma unroll
            for (int h = 0; h < 2; ++h) {
                int m = lm + h * 32;
                int row = mT + m;
                uint4 z; z.x = z.y = z.z = z.w = 0u;
                ra[h] = (row < M) ? *(const uint4*)(A + (size_t)row * K + kn + lkg * 8) : z;
                rw[h] = *(const uint4*)(W + (size_t)(nT + m) * K + kn + lkg * 8);
            }
        }
        #pragma unroll
        for (int S = 0; S < 2; ++S) {
            short8 af[2], bf[2];
            #pragma unroll
            for (int R = 0; R < 2; ++R)
                af[R] = *(const short8*)&As[cur][(wr * 32 + R * 16 + r) * 72 + S * 32 + g * 8];
            #pragma unroll
            for (int C2 = 0; C2 < 2; ++C2)
                bf[C2] = *(const short8*)&Ws[cur][(wcq * 32 + C2 * 16 + r) * 72 + S * 32 + g * 8];
            #pragma unroll
            for (int R = 0; R < 2; ++R)
                #pragma unroll
                for (int C2 = 0; C2 < 2; ++C2)
                    acc[R][C2] = __builtin_amdgcn_mfma_f32_16x16x32_bf16(af[R], bf[C2], acc[R][C2], 0, 0, 0);
        }
        if (more) {
            #pragma unroll
            for (int h = 0; h < 2; ++h) {
                int m = lm + h * 32;
                *(uint4*)&As[cur ^ 1][m * 72 + lkg * 8] = ra[h];
                *(uint4*)&Ws[cur ^ 1][m * 72 + lkg * 8] = rw[h];
            }
        }
        cur ^= 1;
    }

    #pragma unroll
    for (int R = 0; R < 2; ++R)
        #pragma unroll
        for (int C2 = 0; C2 < 2; ++C2)
            #pragma unroll
            for (int q = 0; q < 4; ++q) {
                int mm = mT + wr * 32 + R * 16 + g * 4 + q;
                if (mm >= M) continue;
                int nn = nT + wcq * 32 + C2 * 16 + r;
                float v = acc[R][C2][q];
                if (bias) v += bias[nn];
                if (ACT == 1) v = v > 0.f ? v : expm1f(v);
                if (MASK) { if (maskT[mm % P] != 0) v = 0.f; }
                Y[(size_t)mm * N + nn] = f2b(v);
            }
}

// ---------------------------------------------------------------------------
// split-K GEMM: partials atomicAdd'ed into pre-zeroed f32 Yf.
// ---------------------------------------------------------------------------
__global__ __launch_bounds__(256) void lin_gemm_sk(
    const u16* __restrict__ A, const u16* __restrict__ W,
    float* __restrict__ Yf, int M, int K, int N, int KSTEPS)
{
    __shared__ u16 As[64 * 72];
    __shared__ u16 Ws[64 * 72];
    int tid = threadIdx.x;
    int mT = blockIdx.x * 64, nT = blockIdx.y * 64;
    int kbase = blockIdx.z * KSTEPS * 64;
    int wid = tid >> 6, lane = tid & 63;
    int wr = wid >> 1, wcq = wid & 1;
    int r = lane & 15, g = lane >> 4;
    f32x4 acc[2][2];
    #pragma unroll
    for (int i = 0; i < 2; ++i)
        #pragma unroll
        for (int j = 0; j < 2; ++j)
            acc[i][j] = (f32x4){0.f, 0.f, 0.f, 0.f};

    for (int s = 0; s < KSTEPS; ++s) {
        int k0 = kbase + s * 64;
        #pragma unroll
        for (int h = 0; h < 2; ++h) {
            int gi = tid + h * 256;
            int m = gi >> 3, kg = gi & 7;
            uint4 va = {0u, 0u, 0u, 0u};
            int row = mT + m;
            if (row < M) va = *(const uint4*)(A + (size_t)row * K + k0 + kg * 8);
            *(uint4*)&As[m * 72 + kg * 8] = va;
            *(uint4*)&Ws[m * 72 + kg * 8] = *(const uint4*)(W + (size_t)(nT + m) * K + k0 + kg * 8);
        }
        __syncthreads();
        #pragma unroll
        for (int S = 0; S < 2; ++S) {
            short8 af[2], bf[2];
            #pragma unroll
            for (int R = 0; R < 2; ++R)
                af[R] = *(const short8*)&As[(wr * 32 + R * 16 + r) * 72 + S * 32 + g * 8];
            #pragma unroll
            for (int C2 = 0; C2 < 2; ++C2)
                bf[C2] = *(const short8*)&Ws[(wcq * 32 + C2 * 16 + r) * 72 + S * 32 + g * 8];
            #pragma unroll
            for (int R = 0; R < 2; ++R)
                #pragma unroll
                for (int C2 = 0; C2 < 2; ++C2)
                    acc[R][C2] = __builtin_amdgcn_mfma_f32_16x16x32_bf16(af[R], bf[C2], acc[R][C2], 0, 0, 0);
        }
        __syncthreads();
    }
    #pragma unroll
    for (int R = 0; R < 2; ++R)
        #pragma unroll
        for (int C2 = 0; C2 < 2; ++C2)
            #pragma unroll
            for (int q = 0; q < 4; ++q) {
                int mm = mT + wr * 32 + R * 16 + g * 4 + q;
                if (mm >= M) continue;
                int nn = nT + wcq * 32 + C2 * 16 + r;
                atomicAdd(&Yf[(size_t)mm * N + nn], acc[R][C2][q]);
            }
}

// ---------------------------------------------------------------------------
// epilogue for split-K: bias + ELU + pad-mask + bf16 convert (4 elems/thread)
// ---------------------------------------------------------------------------
__global__ __launch_bounds__(256) void elu_mask_cvt(
    const float* __restrict__ Yf, const float* __restrict__ bias,
    const int* __restrict__ maskT, u16* __restrict__ Y,
    int M, int N, int P)
{
    int t = blockIdx.x * 256 + threadIdx.x;
    int tot = (M * N) >> 2;
    if (t >= tot) return;
    int e0 = t * 4;
    int m = e0 / N, n0 = e0 - m * N;
    float4 v = ((const float4*)Yf)[t];
    float o0 = v.x + bias[n0];
    float o1 = v.y + bias[n0 + 1];
    float o2 = v.z + bias[n0 + 2];
    float o3 = v.w + bias[n0 + 3];
    o0 = o0 > 0.f ? o0 : expm1f(o0);
    o1 = o1 > 0.f ? o1 : expm1f(o1);
    o2 = o2 > 0.f ? o2 : expm1f(o2);
    o3 = o3 > 0.f ? o3 : expm1f(o3);
    if (maskT[m % P] != 0) { o0 = 0.f; o1 = 0.f; o2 = 0.f; o3 = 0.f; }
    uint2 o;
    o.x = (u32)f2b(o0) | ((u32)f2b(o1) << 16);
    o.y = (u32)f2b(o2) | ((u32)f2b(o3) << 16);
    ((uint2*)Y)[t] = o;
}

// ---------------------------------------------------------------------------
// fce via split-K MFMA (f32 weights converted in-register)
// ---------------------------------------------------------------------------
__global__ __launch_bounds__(256) void fce_mfma(
    const u16* __restrict__ A, const float* __restrict__ Wf,
    const float* __restrict__ bias, float* __restrict__ z)
{
    __shared__ u16 As[32 * 72];
    __shared__ u16 Ws[64 * 72];
    int tid = threadIdx.x;
    int nT = blockIdx.x * 64;
    int kbase = blockIdx.y * 256;
    int wv = tid >> 6, lane = tid & 63;
    int r = lane & 15, g = lane >> 4;
    int m = tid >> 3, kg = tid & 7;
    f32x4 acc[2];
    acc[0] = (f32x4){0.f, 0.f, 0.f, 0.f};
    acc[1] = (f32x4){0.f, 0.f, 0.f, 0.f};

    for (int ks = 0; ks < 4; ++ks) {
        int k0 = kbase + ks * 64;
        *(uint4*)&As[m * 72 + kg * 8] = *(const uint4*)(A + (size_t)m * 20480 + k0 + kg * 8);
        #pragma unroll
        for (int h = 0; h < 2; ++h) {
            int row = m + h * 32;
            const float* wr2 = Wf + (size_t)(nT + row) * 20480 + k0 + kg * 8;
            float4 w0 = *(const float4*)(wr2);
            float4 w1 = *(const float4*)(wr2 + 4);
            u16 o[8] = { f2b(w0.x), f2b(w0.y), f2b(w0.z), f2b(w0.w),
                         f2b(w1.x), f2b(w1.y), f2b(w1.z), f2b(w1.w) };
            *(uint4*)&Ws[row * 72 + kg * 8] = *(const uint4*)o;
        }
        __syncthreads();
        #pragma unroll
        for (int S = 0; S < 2; ++S) {
            short8 bfr = *(const short8*)&Ws[(wv * 16 + r) * 72 + S * 32 + g * 8];
            #pragma unroll
            for (int R = 0; R < 2; ++R) {
                short8 af = *(const short8*)&As[(R * 16 + r) * 72 + S * 32 + g * 8];
                acc[R] = __builtin_amdgcn_mfma_f32_16x16x32_bf16(af, bfr, acc[R], 0, 0, 0);
            }
        }
        __syncthreads();
    }
    #pragma unroll
    for (int R = 0; R < 2; ++R)
        #pragma unroll
        for (int q = 0; q < 4; ++q) {
            int mm = R * 16 + g * 4 + q;
            int nn = nT + wv * 16 + r;
            float v = acc[R][q];
            if (blockIdx.y == 0) v += bias[nn];
            atomicAdd(&z[mm * 256 + nn], v);
        }
}

// ---------------------------------------------------------------------------
// fcd via MFMA (both operands f32 -> bf16 in-register)
// ---------------------------------------------------------------------------
__global__ __launch_bounds__(256) void fcd_mfma(
    const float* __restrict__ Af, const float* __restrict__ Wf,
    const float* __restrict__ bias, u16* __restrict__ Y)
{
    __shared__ u16 As[64 * 72];
    __shared__ u16 Ws[64 * 72];
    int tid = threadIdx.x;
    int nT = blockIdx.x * 64;
    int wid = tid >> 6, lane = tid & 63;
    int wr = wid >> 1, wcq = wid & 1;
    int r = lane & 15, g = lane >> 4;
    int m = tid >> 3, kg = tid & 7;
    f32x4 acc[2][2];
    #pragma unroll
    for (int i = 0; i < 2; ++i)
        #pragma unroll
        for (int j = 0; j < 2; ++j)
            acc[i][j] = (f32x4){0.f, 0.f, 0.f, 0.f};

    for (int k0 = 0; k0 < 256; k0 += 64) {
        {
            const float* ar = Af + (size_t)m * 256 + k0 + kg * 8;
            float4 a0 = *(const float4*)(ar);
            float4 a1 = *(const float4*)(ar + 4);
            u16 o[8] = { f2b(a0.x), f2b(a0.y), f2b(a0.z), f2b(a0.w),
                         f2b(a1.x), f2b(a1.y), f2b(a1.z), f2b(a1.w) };
            *(uint4*)&As[m * 72 + kg * 8] = *(const uint4*)o;
            uint4 z4; z4.x = z4.y = z4.z = z4.w = 0u;
            *(uint4*)&As[(m + 32) * 72 + kg * 8] = z4;
        }
        #pragma unroll
        for (int h = 0; h < 2; ++h) {
            int row = m + h * 32;
            const float* wr2 = Wf + (size_t)(nT + row) * 256 + k0 + kg * 8;
            float4 w0 = *(const float4*)(wr2);
            float4 w1 = *(const float4*)(wr2 + 4);
            u16 o[8] = { f2b(w0.x), f2b(w0.y), f2b(w0.z), f2b(w0.w),
                         f2b(w1.x), f2b(w1.y), f2b(w1.z), f2b(w1.w) };
            *(uint4*)&Ws[row * 72 + kg * 8] = *(const uint4*)o;
        }
        __syncthreads();
        #pragma unroll
        for (int S = 0; S < 2; ++S) {
            short8 af[2], bf[2];
            #pragma unroll
            for (int R = 0; R < 2; ++R)
                af[R] = *(const short8*)&As[(wr * 32 + R * 16 + r) * 72 + S * 32 + g * 8];
            #pragma unroll
            for (int C2 = 0; C2 < 2; ++C2)
                bf[C2] = *(const short8*)&Ws[(wcq * 32 + C2 * 16 + r) * 72 + S * 32 + g * 8];
            #pragma unroll
            for (int R = 0; R < 2; ++R)
                #pragma unroll
                for (int C2 = 0; C2 < 2; ++C2)
                    acc[R][C2] = __builtin_amdgcn_mfma_f32_16x16x32_bf16(af[R], bf[C2], acc[R][C2], 0, 0, 0);
        }
        __syncthreads();
    }
    #pragma unroll
    for (int R = 0; R < 2; ++R)
        #pragma unroll
        for (int C2 = 0; C2 < 2; ++C2)
            #pragma unroll
            for (int q = 0; q < 4; ++q) {
                int mm = wr * 32 + R * 16 + g * 4 + q;
                if (mm >= 32) continue;
                int nn = nT + wcq * 32 + C2 * 16 + r;
                float v = acc[R][C2][q] + bias[nn];
                Y[(size_t)mm * 20480 + nn] = f2b(v);
            }
}

// ---------------------------------------------------------------------------
// encoder feast agg (XCD-swizzled)
// ---------------------------------------------------------------------------
template<int F>
__global__ __launch_bounds__(256) void feast_agg(
    const u16* __restrict__ x, const float* __restrict__ cc,
    const int* __restrict__ nbrT, const float* __restrict__ bm,
    u16* __restrict__ agg, int Pin, int P, int Mtot)
{
    constexpr int FC = F / 64;
    __shared__ float s_p[4][81];
    __shared__ int s_nb[4][KN];
    int tid = threadIdx.x, wid = tid >> 6, lane = tid & 63;
    int row = xcd_swz(blockIdx.x, gridDim.x) * 4 + wid;
    bool aw = row < Mtot;
    int b = 0, p = 0;
    if (aw) { b = row / P; p = row - b * P; }
    if (aw && lane < KN) s_nb[wid][lane] = b * Pin + nbrT[p * 12 + lane];
    __syncthreads();

    if (aw && lane < KN) {
        int j = lane;
        const float* c0 = cc + (size_t)s_nb[wid][0] * 16;
        const float* cj = cc + (size_t)s_nb[wid][j] * 16;
        float L[KN];
        #pragma unroll
        for (int i = 0; i < KN; ++i) L[i] = bm[i] + cj[i] - c0[i];
        float mx = L[0];
        #pragma unroll
        for (int i = 1; i < KN; ++i) mx = fmaxf(mx, L[i]);
        float s = 0.f;
        #pragma unroll
        for (int i = 0; i < KN; ++i) { L[i] = __expf(L[i] - mx); s += L[i]; }
        float inv = 1.f / s;
        #pragma unroll
        for (int i = 0; i < KN; ++i) s_p[wid][i * KN + j] = L[i] * inv;
    }
    __syncthreads();

    if (aw) {
        float xn[KN][FC];
        #pragma unroll
        for (int i = 0; i < KN; ++i) {
            const u16* xr = x + (size_t)s_nb[wid][i] * F;
            #pragma unroll
            for (int c = 0; c < FC; ++c) xn[i][c] = b2f(xr[lane + c * 64]);
        }
        #pragma unroll
        for (int j = 0; j < KN; ++j) {
            float a[FC];
            #pragma unroll
            for (int c = 0; c < FC; ++c) a[c] = 0.f;
            #pragma unroll
            for (int i = 0; i < KN; ++i) {
                float pv = s_p[wid][i * KN + j];
                #pragma unroll
                for (int c = 0; c < FC; ++c) a[c] += xn[i][c] * pv;
            }
            u16* orow = agg + (size_t)row * (KN * F) + j * F;
            #pragma unroll
            for (int c = 0; c < FC; ++c) orow[lane + c * 64] = f2b(a[c]);
        }
    }
}

// ---------------------------------------------------------------------------
// decoder mix, 8-wide vectorized G reads, REGISTER-BOUNDED
// ---------------------------------------------------------------------------
template<int C>
__global__ __launch_bounds__(256, 4) void mix_feast_v(
    const u16* __restrict__ G, const float* __restrict__ cc,
    const int* __restrict__ nbrT, const float* __restrict__ bm,
    const float* __restrict__ bc, u16* __restrict__ y,
    int Pin, int P, int Mtot)
{
    constexpr int LPR = C / 8;          // lanes per row: 8 (C=64), 16 (C=128)
    constexpr int RPW = 64 / LPR;       // rows per wave: 8, 4
    constexpr int RPB = 4 * RPW;        // rows per block: 32, 16
    constexpr int GS = KN * C;
    __shared__ float s_p[RPB][84];
    __shared__ int   s_nb[RPB][KN];

    int tid = threadIdx.x, wid = tid >> 6, lane = tid & 63;
    int rowbase = xcd_swz(blockIdx.x, gridDim.x) * RPB;

    for (int t = tid; t < RPB * KN; t += 256) {
        int rr = t / KN, j = t - rr * KN;
        int row = rowbase + rr;
        int v = 0;
        if (row < Mtot) {
            int b = row / P, p = row - b * P;
            v = b * Pin + nbrT[p * 12 + j];
        }
        s_nb[rr][j] = v;
    }
    __syncthreads();

    // softmax columns
    {
        int rl, j0;
        if (C == 64) { rl = wid * RPW + (lane >> 3); j0 = lane & 7; }
        else         { rl = wid * RPW + (lane >> 4); j0 = lane & 15; }
        int row = rowbase + rl;
        if (row < Mtot && j0 <= KN) {
            float cc0[KN], bmr[KN];
            const float* c0 = cc + (size_t)s_nb[rl][0] * 16;
            #pragma unroll
            for (int i = 0; i < KN; ++i) { cc0[i] = c0[i]; bmr[i] = bm[i]; }
            int nj = 1;
            int jl[2]; jl[0] = j0; jl[1] = -1;
            if (C == 64 && j0 == 0) { jl[1] = 8; nj = 2; }
            if (j0 >= KN) nj = 0;
            for (int t = 0; t < nj; ++t) {
                int j = jl[t];
                const float* cj = cc + (size_t)s_nb[rl][j] * 16;
                float L[KN];
                #pragma unroll
                for (int i = 0; i < KN; ++i) L[i] = bmr[i] + cj[i] - cc0[i];
                float mx = L[0];
                #pragma unroll
                for (int i = 1; i < KN; ++i) mx = fmaxf(mx, L[i]);
                float sm = 0.f;
                #pragma unroll
                for (int i = 0; i < KN; ++i) { L[i] = __expf(L[i] - mx); sm += L[i]; }
                float inv = 1.f / sm;
                #pragma unroll
                for (int i = 0; i < KN; ++i) s_p[rl][i * KN + j] = L[i] * inv;
            }
        }
    }
    __syncthreads();

    {
        int rl = wid * RPW + lane / LPR;
        int coff = (lane % LPR) * 8;
        int row = rowbase + rl;
        if (row >= Mtot) return;
        int b = row / P, p = row - b * P;
        (void)b;
        float acc[8];
        #pragma unroll
        for (int k = 0; k < 8; ++k) acc[k] = bc[coff + k];
        #pragma unroll 1
        for (int i = 0; i < KN; ++i) {
            const u16* gr = G + (size_t)s_nb[rl][i] * GS + coff;
            #pragma unroll
            for (int j = 0; j < KN; ++j) {
                uint4 gv = *(const uint4*)(gr + j * C);
                const u16* ge = (const u16*)&gv;
                float p0 = s_p[rl][i * KN + j];
                #pragma unroll
                for (int k = 0; k < 8; ++k) acc[k] += p0 * b2f(ge[k]);
            }
        }
        u16 o[8];
        #pragma unroll
        for (int k = 0; k < 8; ++k) {
            float v = acc[k];
            v = v > 0.f ? v : expm1f(v);
            if (p == P - 1) v = 0.f;
            o[k] = f2b(v);
        }
        *(uint4*)(y + (size_t)row * C + coff) = *(const uint4*)o;
    }
}

// ---------------------------------------------------------------------------
// e0 feast, per-vertex block: grid = 1257 p's; threads = 32 b x 8 cgroups.
// Gathers each neighbor slab ONCE per p (shared across all 32 batches).
// xt: [5024][32][3] f32. y rows b*1257+p, 64 channels bf16.
// ---------------------------------------------------------------------------
__global__ __launch_bounds__(256) void feast_e0p(
    const float* __restrict__ xt, const int* __restrict__ nbr,
    const int* __restrict__ sel,
    const float* __restrict__ wm, const float* __restrict__ bm,
    const float* __restrict__ wc, const float* __restrict__ bc,
    u16* __restrict__ y)
{
    __shared__ float s_x[KN][96];        // [i][b*3+f]
    __shared__ float s_wc[64 * 27];
    __shared__ float s_agg[27][33];      // [q][b], padded
    __shared__ float s_wm[27];
    __shared__ float s_bm[KN];
    __shared__ int   s_nb[KN];

    int tid = threadIdx.x;
    int p = xcd_swz(blockIdx.x, gridDim.x);
    int n = sel[p];
    for (int t = tid; t < 64 * 27; t += 256) s_wc[t] = wc[t];
    if (tid < 27) s_wm[tid] = wm[tid];
    if (tid < KN) s_bm[tid] = bm[tid];
    if (tid < KN) s_nb[tid] = nbr[n * KN + tid];
    __syncthreads();
    for (int t = tid; t < KN * 96; t += 256) {
        int i = t / 96, rr = t - i * 96;
        s_x[i][rr] = xt[(size_t)s_nb[i] * 96 + rr];
    }
    __syncthreads();

    int b = tid >> 3, cg = tid & 7;
    if (cg == 0) {
        float x00 = s_x[0][b * 3], x01 = s_x[0][b * 3 + 1], x02 = s_x[0][b * 3 + 2];
        #pragma unroll 1
        for (int j = 0; j < KN; ++j) {
            float d0 = s_x[j][b * 3]     - x00;
            float d1 = s_x[j][b * 3 + 1] - x01;
            float d2 = s_x[j][b * 3 + 2] - x02;
            float L[KN];
            #pragma unroll
            for (int i = 0; i < KN; ++i)
                L[i] = s_bm[i] + d0 * s_wm[i * 3] + d1 * s_wm[i * 3 + 1] + d2 * s_wm[i * 3 + 2];
            float mx = L[0];
            #pragma unroll
            for (int i = 1; i < KN; ++i) mx = fmaxf(mx, L[i]);
            float sm = 0.f;
            #pragma unroll
            for (int i = 0; i < KN; ++i) { L[i] = __expf(L[i] - mx); sm += L[i]; }
            float inv = 1.f / sm;
            #pragma unroll
            for (int f = 0; f < 3; ++f) {
                float a = 0.f;
                #pragma unroll
                for (int i = 0; i < KN; ++i) a += (L[i] * inv) * s_x[i][b * 3 + f];
                s_agg[f * KN + j][b] = a;
            }
        }
    }
    __syncthreads();

    {
        int c0 = cg * 8;
        float acc[8];
        #pragma unroll
        for (int k = 0; k < 8; ++k) acc[k] = 0.f;
        #pragma unroll 1
        for (int q = 0; q < 27; ++q) {
            float a = s_agg[q][b];
            #pragma unroll
            for (int k = 0; k < 8; ++k) acc[k] += s_wc[(c0 + k) * 27 + q] * a;
        }
        u16 o[8];
        #pragma unroll
        for (int k = 0; k < 8; ++k) {
            float v = acc[k] + bc[c0 + k];
            v = v > 0.f ? v : expm1f(v);
            if (n == 5023) v = 0.f;
            o[k] = f2b(v);
        }
        size_t row = (size_t)b * 1257 + p;
        *(uint4*)(y + row * 64 + c0) = *(const uint4*)o;
    }
}

// ---------------------------------------------------------------------------
// d2 mix, batch-coalesced: lane = batch, wave = 2 vertices x 32 batches.
// ---------------------------------------------------------------------------
__global__ __launch_bounds__(256) void mix_d2t(
    const float* __restrict__ CCT, const float* __restrict__ GWT,
    const int* __restrict__ nbrT,
    const float* __restrict__ bm9, const float* __restrict__ bc3,
    float* __restrict__ out)
{
    __shared__ float s_out[8][32][3];
    int tid = threadIdx.x, wid = tid >> 6, lane = tid & 63;
    int sub = lane >> 5, b = lane & 31;
    int vbase = xcd_swz(blockIdx.x, gridDim.x) * 8;
    int v = vbase + wid * 2 + sub;

    int nbi[KN];
    #pragma unroll
    for (int i = 0; i < KN; ++i) nbi[i] = nbrT[v * 12 + i];
    float bmr[KN];
    #pragma unroll
    for (int i = 0; i < KN; ++i) bmr[i] = bm9[i];

    float cc0[KN];
    {
        const float* c0 = CCT + (size_t)nbi[0] * 9 * 32 + b;
        #pragma unroll
        for (int f = 0; f < KN; ++f) cc0[f] = c0[f * 32];
    }
    float a0 = bc3[0], a1 = bc3[1], a2 = bc3[2];
    #pragma unroll
    for (int j = 0; j < KN; ++j) {
        const float* cj = CCT + (size_t)nbi[j] * 9 * 32 + b;
        float L[KN];
        #pragma unroll
        for (int i = 0; i < KN; ++i) L[i] = bmr[i] + cj[i * 32] - cc0[i];
        float mx = L[0];
        #pragma unroll
        for (int i = 1; i < KN; ++i) mx = fmaxf(mx, L[i]);
        float sm = 0.f;
        #pragma unroll
        for (int i = 0; i < KN; ++i) { L[i] = __expf(L[i] - mx); sm += L[i]; }
        float inv = 1.f / sm;
        #pragma unroll
        for (int i = 0; i < KN; ++i) {
            float pv = L[i] * inv;
            const float* g = GWT + (size_t)nbi[i] * 864 + j * 96 + b * 3;
            a0 += pv * g[0];
            a1 += pv * g[1];
            a2 += pv * g[2];
        }
    }
    if (v == 5023) { a0 = 0.f; a1 = 0.f; a2 = 0.f; }
    s_out[wid * 2 + sub][b][0] = a0;
    s_out[wid * 2 + sub][b][1] = a1;
    s_out[wid * 2 + sub][b][2] = a2;
    __syncthreads();
    {
        int bb = tid >> 3, vi = tid & 7;
        float* dst = out + ((size_t)bb * 5024 + vbase + vi) * 3;
        dst[0] = s_out[vi][bb][0];
        dst[1] = s_out[vi][bb][1];
        dst[2] = s_out[vi][bb][2];
    }
}

// ---------------------------------------------------------------------------
extern "C" void kernel_launch(void* const* d_in, const int* in_sizes, int n_in,
                              void* d_out, int out_size, void* d_ws, size_t ws_size,
                              hipStream_t stream)
{
    const float* x     = (const float*)d_in[0];
    const int*   nbr0  = (const int*)d_in[1];
    const int*   nbr1  = (const int*)d_in[2];
    const int*   nbr2  = (const int*)d_in[3];
    const float* D0    = (const float*)d_in[4];
    const float* U0    = (const float*)d_in[5];
    const float* D1    = (const float*)d_in[6];
    const float* U1    = (const float*)d_in[7];
    const float* D2    = (const float*)d_in[8];
    const float* U2    = (const float*)d_in[9];
    const float* e0_wm = (const float*)d_in[10]; const float* e0_bm = (const float*)d_in[11];
    const float* e0_wc = (const float*)d_in[12]; const float* e0_bc = (const float*)d_in[13];
    const float* e1_wm = (const float*)d_in[14]; const float* e1_bm = (const float*)d_in[15];
    const float* e1_wc = (const float*)d_in[16]; const float* e1_bc = (const float*)d_in[17];
    const float* e2_wm = (const float*)d_in[18]; const float* e2_bm = (const float*)d_in[19];
    const float* e2_wc = (const float*)d_in[20]; const float* e2_bc = (const float*)d_in[21];
    const float* fce_w = (const float*)d_in[22]; const float* fce_b = (const float*)d_in[23];
    const float* fcd_w = (const float*)d_in[24]; const float* fcd_b = (const float*)d_in[25];
    const float* d0_wm = (const float*)d_in[26]; const float* d0_bm = (const float*)d_in[27];
    const float* d0_wc = (const float*)d_in[28]; const float* d0_bc = (const float*)d_in[29];
    const float* d1_wm = (const float*)d_in[30]; const float* d1_bm = (const float*)d_in[31];
    const float* d1_wc = (const float*)d_in[32]; const float* d1_bc = (const float*)d_in[33];
    const float* d2_wm = (const float*)d_in[34]; const float* d2_bm = (const float*)d_in[35];
    const float* d2_wc = (const float*)d_in[36]; const float* d2_bc = (const float*)d_in[37];

    char* w = (char*)d_ws;
    int* idxD0 = (int*)(w);
    int* idxD1 = idxD0 + 1257;
    int* idxD2 = idxD1 + 315;
    int* idxU0 = idxD2 + 80;
    int* idxU1 = idxU0 + 5024;
    int* idxU2 = idxU1 + 1257;
    int* nbrD1  = (int*)(w + 33024);
    int* nbrD2  = (int*)(w + 48144);
    int* nbrU2  = (int*)(w + 51984);
    int* nbrU1  = (int*)(w + 67104);
    int* nbrU0  = (int*)(w + 127440);
    int* maskE1 = (int*)(w + 368640);
    int* maskE2 = (int*)(w + 369920);
    u16* wcrE1 = (u16*)(w + 370432);
    u16* wcrE2 = (u16*)(w + 517888);
    u16* wg0   = (u16*)(w + 1107712);
    u16* wg1   = (u16*)(w + 1697536);
    u16* ccwE1 = (u16*)(w + 1844992);
    u16* ccwE2 = (u16*)(w + 1853184);
    u16* ccwD0 = (u16*)(w + 1869568);
    u16* ccwD1 = (u16*)(w + 1902336);
    u16* w3    = (u16*)(w + 1918720);
    float* zbuf = (float*)(w + 1926912);

    u16*   X1   = (u16*)  (w + 2097152);
    float* CC1  = (float*)(w + 7245824);
    u16*   AGG1 = (u16*)  (w + 9820160);
    u16*   X2   = (u16*)  (w + 21432320);
    float* CC2  = (float*)(w + 24012800);
    u16*   AGG2 = (u16*)  (w + 24657920);
    u16*   X3   = (u16*)  (w + 2097152);
    u16*   X3P  = (u16*)  (w + 3407872);
    float* CCD0 = (float*)(w + 4718592);
    u16*   G0   = (u16*)  (w + 4882432);
    u16*   XD1P = (u16*)  (w + 10780672);
    float* CCD1 = (float*)(w + 13361152);
    u16*   G1   = (u16*)  (w + 14006272);
    u16*   XD2P = (u16*)  (w + 25618432);
    float* CCT  = (float*)(w + 30767104);
    float* GWT  = (float*)(w + 32215168);
    float* X2F  = (float*)(w + 36559360);
    float* X3F  = (float*)(w + 41720320);   // -> 44341760
    float* XT   = (float*)(w + 44341760);   // [5024][32][3] f32 -> 46270976

    // prep
    extract_idx_all<<<8248, 256, 0, stream>>>(D0, D1, D2, U0, U1, U2,
                                              idxD0, idxD1, idxD2, idxU0, idxU1, idxU2);
    cvt_weights<<<3072, 256, 0, stream>>>(e1_wc, e2_wc, d0_wc, d1_wc,
                                          e1_wm, e2_wm, d0_wm, d1_wm, d2_wm, d2_wc,
                                          wcrE1, wcrE2, wg0, wg1,
                                          ccwE1, ccwE2, ccwD0, ccwD1, w3, zbuf);
    compose_tables<<<248, 256, 0, stream>>>(nbr0, nbr1, nbr2,
                                            idxD1, idxD2, idxU0, idxU1, idxU2,
                                            nbrD1, nbrD2, nbrU2, nbrU1, nbrU0,
                                            maskE1, maskE2);
    zero_f32<<<1900, 256, 0, stream>>>((float4*)X2F, 486400);   // X2F + X3F
    xpose_x<<<1884, 256, 0, stream>>>(x, XT);

    // ---- encoder ----
    feast_e0p<<<1257, 256, 0, stream>>>(XT, nbr0, idxD0, e0_wm, e0_bm, e0_wc, e0_bc, X1);
    cc_gemm<16, 16><<<629, 256, 0, stream>>>(X1, ccwE1, CC1, 40224, 64);
    feast_agg<64><<<2520, 256, 0, stream>>>(X1, CC1, nbrD1, e1_bm, AGG1, 1257, 315, 10080);
    lin_gemm_sk<<<dim3(158, 2, 3), 256, 0, stream>>>(AGG1, wcrE1, X2F, 10080, 576, 128, 3);
    elu_mask_cvt<<<1260, 256, 0, stream>>>(X2F, e1_bc, maskE1, X2, 10080, 128, 315);
    cc_gemm<16, 16><<<158, 256, 0, stream>>>(X2, ccwE2, CC2, 10080, 128);
    feast_agg<128><<<640, 256, 0, stream>>>(X2, CC2, nbrD2, e2_bm, AGG2, 315, 80, 2560);
    lin_gemm_sk<<<dim3(40, 4, 6), 256, 0, stream>>>(AGG2, wcrE2, X3F, 2560, 1152, 256, 3);
    elu_mask_cvt<<<640, 256, 0, stream>>>(X3F, e2_bc, maskE2, X3, 2560, 256, 80);

    // ---- bottleneck ----
    fce_mfma<<<dim3(4, 80), 256, 0, stream>>>(X3, fce_w, fce_b, zbuf);
    fcd_mfma<<<320, 256, 0, stream>>>(zbuf, fcd_w, fcd_b, X3P);

    // ---- decoder ----
    cc_gemm<16, 16><<<40, 256, 0, stream>>>(X3P, ccwD0, CCD0, 2560, 256);
    lin_gemm<0, 0><<<dim3(40, 18), 256, 0, stream>>>(X3P, wg0, nullptr, G0, nullptr,
                                                     2560, 256, 1152, 1);
    mix_feast_v<128><<<630, 256, 0, stream>>>(G0, CCD0, nbrU2, d0_bm, d0_bc, XD1P,
                                              80, 315, 10080);
    cc_gemm<16, 16><<<158, 256, 0, stream>>>(XD1P, ccwD1, CCD1, 10080, 128);
    lin_gemm<0, 0><<<dim3(158, 9), 256, 0, stream>>>(XD1P, wg1, nullptr, G1, nullptr,
                                                     10080, 128, 576, 1);
    mix_feast_v<64><<<1257, 256, 0, stream>>>(G1, CCD1, nbrU1, d1_bm, d1_bc, XD2P,
                                              315, 1257, 40224);
    cc_gemmT<<<629, 256, 0, stream>>>(XD2P, w3, CCT, GWT, 40224);
    mix_d2t<<<628, 256, 0, stream>>>(CCT, GWT, nbrU0, d2_bm, d2_bc, (float*)d_out);
}